// Round 8
// baseline (281.728 us; speedup 1.0000x reference)
//
#include <hip/hip_runtime.h>
#include <math.h>

// Problem constants (B=1)
#define S_LEN 2048
#define D_DIM 512
#define H_NUM 8
#define HD    64
#define C_NUM 32
#define TOPK  5
#define SCALE 0.125f   // hd^-0.5
#define GSPLIT 8       // blocks per (h,c) pair in moc_attn3
#define QCAP  1024     // fixed qlist capacity per (h,c); load is 320±16

// ---------------------------------------------------------------------------
// GEMM: C[M,N] = A[M,K] @ B[K,N], fp32 vector-ALU, 64x64 tile, BK=32,
// 256 threads, 4x4 micro-tile. Software-pipelined: next k-tile's global
// loads are issued right after the LDS store barrier, overlapping the
// 32-step FMA loop (previously the load latency was fully exposed).
// NORM: divide A rows by lacc[(kcol>>6)][row] at load time (folds the
// attention normalization pass into the final GEMM).
// ---------------------------------------------------------------------------
#define BM 64
#define BN 64
#define BK 32

template <bool NORM>
__device__ __forceinline__ void gemm_body(const float* __restrict__ A,
                                          const float* __restrict__ B,
                                          float* __restrict__ C,
                                          int M, int N, int K,
                                          int bx, int by,
                                          const float* __restrict__ lacc) {
    __shared__ float As[BK][BM + 4];
    __shared__ float Bs[BK][BN];

    const int t  = threadIdx.x;
    const int tx = t & 15;
    const int ty = t >> 4;
    const int m0 = by * BM;
    const int n0 = bx * BN;

    float4 acc0 = make_float4(0.f,0.f,0.f,0.f);
    float4 acc1 = make_float4(0.f,0.f,0.f,0.f);
    float4 acc2 = make_float4(0.f,0.f,0.f,0.f);
    float4 acc3 = make_float4(0.f,0.f,0.f,0.f);

    const int ar = t >> 3;        // 0..31
    const int ac = (t & 7) * 4;   // 0..28
    const int br = t >> 4;        // 0..15
    const int bc = (t & 15) * 4;  // 0..60

    float4 a0, a1, b0, b1;
    auto LD = [&](int k0) {
        a0 = *(const float4*)&A[(size_t)(m0 + ar)      * K + k0 + ac];
        a1 = *(const float4*)&A[(size_t)(m0 + ar + 32) * K + k0 + ac];
        b0 = *(const float4*)&B[(size_t)(k0 + br)      * N + n0 + bc];
        b1 = *(const float4*)&B[(size_t)(k0 + br + 16) * N + n0 + bc];
        if (NORM) {
            // cols k0+ac..+3 are 4-aligned -> same 64-block -> one h each
            int hcol = (k0 + ac) >> 6;
            float inv0 = 1.0f / lacc[hcol * S_LEN + (m0 + ar)];
            float inv1 = 1.0f / lacc[hcol * S_LEN + (m0 + ar + 32)];
            a0.x *= inv0; a0.y *= inv0; a0.z *= inv0; a0.w *= inv0;
            a1.x *= inv1; a1.y *= inv1; a1.z *= inv1; a1.w *= inv1;
        }
    };

    LD(0);
    for (int k0 = 0; k0 < K; k0 += BK) {
        __syncthreads();   // previous iteration's LDS reads done
        As[ac+0][ar]    = a0.x; As[ac+1][ar]    = a0.y; As[ac+2][ar]    = a0.z; As[ac+3][ar]    = a0.w;
        As[ac+0][ar+32] = a1.x; As[ac+1][ar+32] = a1.y; As[ac+2][ar+32] = a1.z; As[ac+3][ar+32] = a1.w;
        *(float4*)&Bs[br][bc]      = b0;
        *(float4*)&Bs[br + 16][bc] = b1;
        __syncthreads();

        if (k0 + BK < K) LD(k0 + BK);   // overlaps the compute below

        #pragma unroll
        for (int kk = 0; kk < BK; ++kk) {
            float4 a = *(const float4*)&As[kk][ty * 4];
            float4 b = *(const float4*)&Bs[kk][tx * 4];
            acc0.x += a.x*b.x; acc0.y += a.x*b.y; acc0.z += a.x*b.z; acc0.w += a.x*b.w;
            acc1.x += a.y*b.x; acc1.y += a.y*b.y; acc1.z += a.y*b.z; acc1.w += a.y*b.w;
            acc2.x += a.z*b.x; acc2.y += a.z*b.y; acc2.z += a.z*b.z; acc2.w += a.z*b.w;
            acc3.x += a.w*b.x; acc3.y += a.w*b.y; acc3.z += a.w*b.z; acc3.w += a.w*b.w;
        }
    }

    *(float4*)&C[(size_t)(m0 + ty*4 + 0) * N + n0 + tx*4] = acc0;
    *(float4*)&C[(size_t)(m0 + ty*4 + 1) * N + n0 + tx*4] = acc1;
    *(float4*)&C[(size_t)(m0 + ty*4 + 2) * N + n0 + tx*4] = acc2;
    *(float4*)&C[(size_t)(m0 + ty*4 + 3) * N + n0 + tx*4] = acc3;
}

// Fused Q/K/V projections: blockIdx.z selects weight/output -> 768 blocks.
__global__ __launch_bounds__(256) void gemm_qkv(const float* __restrict__ A,
                                                const float* __restrict__ Wq,
                                                const float* __restrict__ Wk,
                                                const float* __restrict__ Wv,
                                                float* __restrict__ Qb,
                                                float* __restrict__ Kb,
                                                float* __restrict__ Vb) {
    const float* B = (blockIdx.z == 0) ? Wq : (blockIdx.z == 1) ? Wk : Wv;
    float*       C = (blockIdx.z == 0) ? Qb : (blockIdx.z == 1) ? Kb : Vb;
    gemm_body<false>(A, B, C, S_LEN, D_DIM, D_DIM, blockIdx.x, blockIdx.y, nullptr);
}

// Final projection with attention-normalization folded into the A-load.
__global__ __launch_bounds__(256) void gemm_out(const float* __restrict__ Ob,
                                                const float* __restrict__ Wo,
                                                float* __restrict__ out,
                                                const float* __restrict__ lacc) {
    gemm_body<true>(Ob, Wo, out, S_LEN, D_DIM, D_DIM, blockIdx.x, blockIdx.y, lacc);
}

// ---------------------------------------------------------------------------
// Zero accumulators (graph-capture-safe: kernels only). float4 writes.
// grid = 1024 blocks: covers Ob (4MB = 262144 float4), lacc, cur.
// ---------------------------------------------------------------------------
__global__ __launch_bounds__(256) void zero_acc(float4* __restrict__ Ob4,
                                                float4* __restrict__ lacc4,
                                                int* __restrict__ cur) {
    int i = blockIdx.x * 256 + threadIdx.x;
    Ob4[i] = make_float4(0.f,0.f,0.f,0.f);
    if (i < (H_NUM * S_LEN) / 4) lacc4[i] = make_float4(0.f,0.f,0.f,0.f);
    if (i < 256) cur[i] = 0;
}

// ---------------------------------------------------------------------------
// chunk_keys[c][dcol] = mean over 64 rows of K[(c*64+r)][dcol]; ck is [32][512]
// ---------------------------------------------------------------------------
__global__ __launch_bounds__(256) void chunk_keys_kernel(const float* __restrict__ K,
                                                         float* __restrict__ ck) {
    int i = blockIdx.x * 256 + threadIdx.x;    // 0..16383
    int c = i >> 9;
    int d = i & 511;
    const float* p = K + (size_t)c * 64 * D_DIM + d;
    float sum = 0.f;
    #pragma unroll
    for (int r = 0; r < 64; ++r) sum += p[(size_t)r * D_DIM];
    ck[(size_t)c * D_DIM + d] = sum * (1.0f / 64.0f);
}

// ---------------------------------------------------------------------------
// Fused sims + top-5 + scatter (unchanged from round 7 — passing, ~fast).
// ---------------------------------------------------------------------------
__global__ __launch_bounds__(256) void sims_topk(const float* __restrict__ Q,
                                                 const float* __restrict__ ck,
                                                 int* __restrict__ cur,
                                                 unsigned short* __restrict__ qlist) {
    __shared__ float qtile[64][68];
    __shared__ float cks[32][68];
    __shared__ float simsb[64][36];
    __shared__ int   lds_cnt[32];
    __shared__ int   lds_base[32];

    const int t  = threadIdx.x;
    const int s0 = blockIdx.x * 64;
    const int h  = blockIdx.y;

    if (t < 32) lds_cnt[t] = 0;

    {
        int r = t >> 2;
        #pragma unroll
        for (int i = 0; i < 4; ++i) {
            int cf4 = (t & 3) * 4 + i;
            *(float4*)&qtile[r][cf4 * 4] =
                *(const float4*)&Q[(size_t)(s0 + r) * D_DIM + h * HD + cf4 * 4];
        }
    }
    for (int i = t; i < C_NUM * 16; i += 256) {
        int c = i >> 4, df4 = i & 15;
        *(float4*)&cks[c][df4 * 4] =
            *(const float4*)&ck[(size_t)c * D_DIM + h * HD + df4 * 4];
    }
    __syncthreads();

    {
        const int sl = t >> 2, g = t & 3;
        float sa[8] = {0.f,0.f,0.f,0.f,0.f,0.f,0.f,0.f};
        #pragma unroll
        for (int d4 = 0; d4 < 16; ++d4) {
            float4 q4 = *(const float4*)&qtile[sl][d4 * 4];
            #pragma unroll
            for (int j = 0; j < 8; ++j) {
                float4 c4 = *(const float4*)&cks[g * 8 + j][d4 * 4];
                sa[j] += q4.x*c4.x + q4.y*c4.y + q4.z*c4.z + q4.w*c4.w;
            }
        }
        *(float4*)&simsb[sl][g*8 + 0] = make_float4(sa[0], sa[1], sa[2], sa[3]);
        *(float4*)&simsb[sl][g*8 + 4] = make_float4(sa[4], sa[5], sa[6], sa[7]);
    }
    __syncthreads();

    int csel[TOPK], lpos[TOPK];
    if (t < 64) {
        float sv[32];
        #pragma unroll
        for (int cq = 0; cq < 8; ++cq) {
            float4 v = *(const float4*)&simsb[t][cq * 4];
            sv[cq*4+0] = v.x; sv[cq*4+1] = v.y; sv[cq*4+2] = v.z; sv[cq*4+3] = v.w;
        }
        #pragma unroll
        for (int k = 0; k < TOPK; ++k) {
            float best = -INFINITY; int bi = 0;
            #pragma unroll
            for (int cc = 0; cc < 32; ++cc) {
                bool gt = sv[cc] > best;
                best = gt ? sv[cc] : best;
                bi   = gt ? cc : bi;
            }
            #pragma unroll
            for (int cc = 0; cc < 32; ++cc)
                if (cc == bi) sv[cc] = -INFINITY;
            csel[k] = bi;
            lpos[k] = atomicAdd(&lds_cnt[bi], 1);
        }
    }
    __syncthreads();

    if (t < 32) lds_base[t] = atomicAdd(&cur[h * 32 + t], lds_cnt[t]);
    __syncthreads();

    if (t < 64) {
        #pragma unroll
        for (int k = 0; k < TOPK; ++k) {
            int c = csel[k];
            int pos = lds_base[c] + lpos[k];
            if (pos < QCAP)
                qlist[(size_t)(h * 32 + c) * QCAP + pos] = (unsigned short)(s0 + t);
        }
    }
}

// ---------------------------------------------------------------------------
// Chunk-centric sparse attention v3. Same algorithm as moc_attn2, three
// latency fixes:
//  - denominator from PV-loop p sums (kills the 6-shuffle serial chain)
//  - 2 queries per iteration (two independent LDS/exp chains overlap)
//  - next pair's list/Q loads prefetched under current compute
//  - GSPLIT 8, contiguous per-slot query ranges (balance + L2 locality)
// ---------------------------------------------------------------------------
__global__ __launch_bounds__(256) void moc_attn3(const float* __restrict__ Q,
                                                 const float* __restrict__ K,
                                                 const float* __restrict__ V,
                                                 const int* __restrict__ cnt,
                                                 const unsigned short* __restrict__ qlist,
                                                 float* __restrict__ lacc,
                                                 float* __restrict__ Ob) {
    __shared__ float stage[64][68];
    __shared__ float qs[4][2][64];
    __shared__ float ps[4][2][64];

    const int hc   = blockIdx.y;
    const int h    = hc >> 5;
    const int c    = hc & 31;
    const int g    = blockIdx.x;       // 0..GSPLIT-1
    const int t    = threadIdx.x;
    const int widx = t >> 6;
    const int lane = t & 63;

    const float* Kb = K + ((size_t)c * 64) * D_DIM + h * HD;
    const float* Vb = V + ((size_t)c * 64) * D_DIM + h * HD;

    // K rows -> registers: lane j holds K[j][0..63]
    float4 kreg[16];
    #pragma unroll
    for (int dq = 0; dq < 16; ++dq)
        kreg[dq] = *(const float4*)&Kb[(size_t)lane * D_DIM + dq * 4];

    // V -> LDS (coalesced) -> transpose to registers: lane d holds V[:,d]
    for (int i = t; i < 64 * 16; i += 256) {
        int r = i >> 4, cq = i & 15;
        *(float4*)&stage[r][cq * 4] = *(const float4*)&Vb[(size_t)r * D_DIM + cq * 4];
    }
    __syncthreads();
    float4 vreg[16];
    #pragma unroll
    for (int jq = 0; jq < 16; ++jq)
        vreg[jq] = make_float4(stage[4*jq+0][lane], stage[4*jq+1][lane],
                               stage[4*jq+2][lane], stage[4*jq+3][lane]);

    const int count = min(cnt[hc], QCAP);
    const unsigned short* list = qlist + (size_t)hc * QCAP;
    const int slot = g * 4 + widx;                 // 0..31
    int lo = (count * slot) >> 5;
    int hi = (count * (slot + 1)) >> 5;

    const float* Qh = Q + h * HD + lane;

    int sa = 0, sb = 0; float qa = 0.f, qb = 0.f;
    if (lo < hi)     { sa = list[lo];     qa = Qh[(size_t)sa * D_DIM]; }
    if (lo + 1 < hi) { sb = list[lo + 1]; qb = Qh[(size_t)sb * D_DIM]; }

    for (int i = lo; i < hi; i += 2) {
        int   csa = sa,  csb = sb;
        float cqa = qa,  cqb = qb;
        bool hasb = (i + 1 < hi);
        if (!hasb) { csb = csa; cqb = cqa; }       // compute dup, skip its atomics

        int in = i + 2;                            // prefetch next pair
        if (in < hi)     { sa = list[in];     qa = Qh[(size_t)sa * D_DIM]; }
        if (in + 1 < hi) { sb = list[in + 1]; qb = Qh[(size_t)sb * D_DIM]; }

        qs[widx][0][lane] = cqa;
        qs[widx][1][lane] = cqb;

        float sca = 0.f, scb = 0.f;
        #pragma unroll
        for (int dq = 0; dq < 16; ++dq) {
            float4 qba = *(const float4*)&qs[widx][0][dq * 4];  // broadcast
            float4 qbb = *(const float4*)&qs[widx][1][dq * 4];
            sca += qba.x*kreg[dq].x + qba.y*kreg[dq].y + qba.z*kreg[dq].z + qba.w*kreg[dq].w;
            scb += qbb.x*kreg[dq].x + qbb.y*kreg[dq].y + qbb.z*kreg[dq].z + qbb.w*kreg[dq].w;
        }
        float pea = __expf(sca * SCALE);
        float peb = __expf(scb * SCALE);
        ps[widx][0][lane] = pea;
        ps[widx][1][lane] = peb;

        float oa = 0.f, ob = 0.f, lsa = 0.f, lsb = 0.f;
        #pragma unroll
        for (int jq = 0; jq < 16; ++jq) {
            float4 p4a = *(const float4*)&ps[widx][0][jq * 4];  // broadcast
            float4 p4b = *(const float4*)&ps[widx][1][jq * 4];
            oa  += p4a.x*vreg[jq].x + p4a.y*vreg[jq].y + p4a.z*vreg[jq].z + p4a.w*vreg[jq].w;
            ob  += p4b.x*vreg[jq].x + p4b.y*vreg[jq].y + p4b.z*vreg[jq].z + p4b.w*vreg[jq].w;
            lsa += p4a.x + p4a.y + p4a.z + p4a.w;   // denominator for free
            lsb += p4b.x + p4b.y + p4b.z + p4b.w;
        }

        atomicAdd(&Ob[(size_t)csa * D_DIM + h * HD + lane], oa);
        if (hasb) atomicAdd(&Ob[(size_t)csb * D_DIM + h * HD + lane], ob);
        if (lane == 0) {
            atomicAdd(&lacc[h * S_LEN + csa], lsa);
            if (hasb) atomicAdd(&lacc[h * S_LEN + csb], lsb);
        }
    }
}

// ---------------------------------------------------------------------------
// Workspace: Qb 4MB | Kb 4MB | Vb 4MB | Ob 4MB | ck 64KB | lacc 64KB
//            | cur 1KB | qlist (ushort, 512KB)  == 17,433,600 B total
// (identical layout to passing round 7)
// ---------------------------------------------------------------------------
extern "C" void kernel_launch(void* const* d_in, const int* in_sizes, int n_in,
                              void* d_out, int out_size, void* d_ws, size_t ws_size,
                              hipStream_t stream) {
    const float* x  = (const float*)d_in[0];
    const float* Wq = (const float*)d_in[1];
    const float* Wk = (const float*)d_in[2];
    const float* Wv = (const float*)d_in[3];
    const float* Wo = (const float*)d_in[4];
    float* out = (float*)d_out;

    const size_t SD = (size_t)S_LEN * D_DIM;   // 1048576
    float* ws   = (float*)d_ws;
    float* Qb   = ws;
    float* Kb   = Qb + SD;
    float* Vb   = Kb + SD;
    float* Ob   = Vb + SD;
    float* ck   = Ob + SD;                       // [32][512]
    float* lacc = ck + (size_t)C_NUM * D_DIM;    // [H][S]
    int*   curb = (int*)(lacc + (size_t)H_NUM * S_LEN);        // [256]
    unsigned short* qlst = (unsigned short*)(curb + 256);      // [256][QCAP]

    zero_acc<<<(int)(SD / 4 / 256), 256, 0, stream>>>((float4*)Ob, (float4*)lacc, curb);

    dim3 qkvgrid(D_DIM / BN, S_LEN / BM, 3);     // 768 blocks
    gemm_qkv<<<qkvgrid, 256, 0, stream>>>(x, Wq, Wk, Wv, Qb, Kb, Vb);

    chunk_keys_kernel<<<(C_NUM * D_DIM) / 256, 256, 0, stream>>>(Kb, ck);

    dim3 rgrid(S_LEN / 64, H_NUM);               // (32, 8)
    sims_topk<<<rgrid, 256, 0, stream>>>(Qb, ck, curb, qlst);

    dim3 agrid(GSPLIT, H_NUM * C_NUM);           // (8, 256)
    moc_attn3<<<agrid, 256, 0, stream>>>(Qb, Kb, Vb, curb, qlst, lacc, Ob);

    dim3 ogrid(D_DIM / BN, S_LEN / BM);          // (8, 32)
    gemm_out<<<ogrid, 256, 0, stream>>>(Ob, Wo, out, lacc);
}

// Round 9
// 241.030 us; speedup vs baseline: 1.1689x; 1.1689x over previous
//
#include <hip/hip_runtime.h>
#include <math.h>

// Problem constants (B=1)
#define S_LEN 2048
#define D_DIM 512
#define H_NUM 8
#define HD    64
#define C_NUM 32
#define TOPK  5
#define SCALE 0.125f   // hd^-0.5
#define AGSPLIT 3      // query-range slots per (h,c) in moc_attn4
#define QCAP  1024     // fixed qlist capacity per (h,c); load is 320±16

// ---------------------------------------------------------------------------
// GEMM: C[M,N] = A[M,K] @ B[K,N], fp32 vector-ALU, 64x64 tile, BK=32,
// software-pipelined global loads. NORM folds attention normalization
// (divide A rows by lacc) into the A-load of the final projection.
// ---------------------------------------------------------------------------
#define BM 64
#define BN 64
#define BK 32

template <bool NORM>
__device__ __forceinline__ void gemm_body(const float* __restrict__ A,
                                          const float* __restrict__ B,
                                          float* __restrict__ C,
                                          int M, int N, int K,
                                          int bx, int by,
                                          const float* __restrict__ lacc) {
    __shared__ float As[BK][BM + 4];
    __shared__ float Bs[BK][BN];

    const int t  = threadIdx.x;
    const int tx = t & 15;
    const int ty = t >> 4;
    const int m0 = by * BM;
    const int n0 = bx * BN;

    float4 acc0 = make_float4(0.f,0.f,0.f,0.f);
    float4 acc1 = make_float4(0.f,0.f,0.f,0.f);
    float4 acc2 = make_float4(0.f,0.f,0.f,0.f);
    float4 acc3 = make_float4(0.f,0.f,0.f,0.f);

    const int ar = t >> 3;        // 0..31
    const int ac = (t & 7) * 4;   // 0..28
    const int br = t >> 4;        // 0..15
    const int bc = (t & 15) * 4;  // 0..60

    float4 a0, a1, b0, b1;
    auto LD = [&](int k0) {
        a0 = *(const float4*)&A[(size_t)(m0 + ar)      * K + k0 + ac];
        a1 = *(const float4*)&A[(size_t)(m0 + ar + 32) * K + k0 + ac];
        b0 = *(const float4*)&B[(size_t)(k0 + br)      * N + n0 + bc];
        b1 = *(const float4*)&B[(size_t)(k0 + br + 16) * N + n0 + bc];
        if (NORM) {
            int hcol = (k0 + ac) >> 6;
            float inv0 = 1.0f / lacc[hcol * S_LEN + (m0 + ar)];
            float inv1 = 1.0f / lacc[hcol * S_LEN + (m0 + ar + 32)];
            a0.x *= inv0; a0.y *= inv0; a0.z *= inv0; a0.w *= inv0;
            a1.x *= inv1; a1.y *= inv1; a1.z *= inv1; a1.w *= inv1;
        }
    };

    LD(0);
    for (int k0 = 0; k0 < K; k0 += BK) {
        __syncthreads();
        As[ac+0][ar]    = a0.x; As[ac+1][ar]    = a0.y; As[ac+2][ar]    = a0.z; As[ac+3][ar]    = a0.w;
        As[ac+0][ar+32] = a1.x; As[ac+1][ar+32] = a1.y; As[ac+2][ar+32] = a1.z; As[ac+3][ar+32] = a1.w;
        *(float4*)&Bs[br][bc]      = b0;
        *(float4*)&Bs[br + 16][bc] = b1;
        __syncthreads();

        if (k0 + BK < K) LD(k0 + BK);

        #pragma unroll
        for (int kk = 0; kk < BK; ++kk) {
            float4 a = *(const float4*)&As[kk][ty * 4];
            float4 b = *(const float4*)&Bs[kk][tx * 4];
            acc0.x += a.x*b.x; acc0.y += a.x*b.y; acc0.z += a.x*b.z; acc0.w += a.x*b.w;
            acc1.x += a.y*b.x; acc1.y += a.y*b.y; acc1.z += a.y*b.z; acc1.w += a.y*b.w;
            acc2.x += a.z*b.x; acc2.y += a.z*b.y; acc2.z += a.z*b.z; acc2.w += a.z*b.w;
            acc3.x += a.w*b.x; acc3.y += a.w*b.y; acc3.z += a.w*b.z; acc3.w += a.w*b.w;
        }
    }

    *(float4*)&C[(size_t)(m0 + ty*4 + 0) * N + n0 + tx*4] = acc0;
    *(float4*)&C[(size_t)(m0 + ty*4 + 1) * N + n0 + tx*4] = acc1;
    *(float4*)&C[(size_t)(m0 + ty*4 + 2) * N + n0 + tx*4] = acc2;
    *(float4*)&C[(size_t)(m0 + ty*4 + 3) * N + n0 + tx*4] = acc3;
}

__global__ __launch_bounds__(256) void gemm_qkv(const float* __restrict__ A,
                                                const float* __restrict__ Wq,
                                                const float* __restrict__ Wk,
                                                const float* __restrict__ Wv,
                                                float* __restrict__ Qb,
                                                float* __restrict__ Kb,
                                                float* __restrict__ Vb) {
    const float* B = (blockIdx.z == 0) ? Wq : (blockIdx.z == 1) ? Wk : Wv;
    float*       C = (blockIdx.z == 0) ? Qb : (blockIdx.z == 1) ? Kb : Vb;
    gemm_body<false>(A, B, C, S_LEN, D_DIM, D_DIM, blockIdx.x, blockIdx.y, nullptr);
}

__global__ __launch_bounds__(256) void gemm_out(const float* __restrict__ Ob,
                                                const float* __restrict__ Wo,
                                                float* __restrict__ out,
                                                const float* __restrict__ lacc) {
    gemm_body<true>(Ob, Wo, out, S_LEN, D_DIM, D_DIM, blockIdx.x, blockIdx.y, lacc);
}

// ---------------------------------------------------------------------------
// Zero accumulators (graph-capture-safe: kernels only).
// ---------------------------------------------------------------------------
__global__ __launch_bounds__(256) void zero_acc(float4* __restrict__ Ob4,
                                                float4* __restrict__ lacc4,
                                                int* __restrict__ cur) {
    int i = blockIdx.x * 256 + threadIdx.x;
    Ob4[i] = make_float4(0.f,0.f,0.f,0.f);
    if (i < (H_NUM * S_LEN) / 4) lacc4[i] = make_float4(0.f,0.f,0.f,0.f);
    if (i < 256) cur[i] = 0;
}

// ---------------------------------------------------------------------------
// chunk_keys[c][dcol] = mean over 64 rows of K[(c*64+r)][dcol]; ck is [32][512]
// ---------------------------------------------------------------------------
__global__ __launch_bounds__(256) void chunk_keys_kernel(const float* __restrict__ K,
                                                         float* __restrict__ ck) {
    int i = blockIdx.x * 256 + threadIdx.x;    // 0..16383
    int c = i >> 9;
    int d = i & 511;
    const float* p = K + (size_t)c * 64 * D_DIM + d;
    float sum = 0.f;
    #pragma unroll
    for (int r = 0; r < 64; ++r) sum += p[(size_t)r * D_DIM];
    ck[(size_t)c * D_DIM + d] = sum * (1.0f / 64.0f);
}

// ---------------------------------------------------------------------------
// Fused sims + top-5 + scatter (unchanged — proven in round 7).
// ---------------------------------------------------------------------------
__global__ __launch_bounds__(256) void sims_topk(const float* __restrict__ Q,
                                                 const float* __restrict__ ck,
                                                 int* __restrict__ cur,
                                                 unsigned short* __restrict__ qlist) {
    __shared__ float qtile[64][68];
    __shared__ float cks[32][68];
    __shared__ float simsb[64][36];
    __shared__ int   lds_cnt[32];
    __shared__ int   lds_base[32];

    const int t  = threadIdx.x;
    const int s0 = blockIdx.x * 64;
    const int h  = blockIdx.y;

    if (t < 32) lds_cnt[t] = 0;

    {
        int r = t >> 2;
        #pragma unroll
        for (int i = 0; i < 4; ++i) {
            int cf4 = (t & 3) * 4 + i;
            *(float4*)&qtile[r][cf4 * 4] =
                *(const float4*)&Q[(size_t)(s0 + r) * D_DIM + h * HD + cf4 * 4];
        }
    }
    for (int i = t; i < C_NUM * 16; i += 256) {
        int c = i >> 4, df4 = i & 15;
        *(float4*)&cks[c][df4 * 4] =
            *(const float4*)&ck[(size_t)c * D_DIM + h * HD + df4 * 4];
    }
    __syncthreads();

    {
        const int sl = t >> 2, g = t & 3;
        float sa[8] = {0.f,0.f,0.f,0.f,0.f,0.f,0.f,0.f};
        #pragma unroll
        for (int d4 = 0; d4 < 16; ++d4) {
            float4 q4 = *(const float4*)&qtile[sl][d4 * 4];
            #pragma unroll
            for (int j = 0; j < 8; ++j) {
                float4 c4 = *(const float4*)&cks[g * 8 + j][d4 * 4];
                sa[j] += q4.x*c4.x + q4.y*c4.y + q4.z*c4.z + q4.w*c4.w;
            }
        }
        *(float4*)&simsb[sl][g*8 + 0] = make_float4(sa[0], sa[1], sa[2], sa[3]);
        *(float4*)&simsb[sl][g*8 + 4] = make_float4(sa[4], sa[5], sa[6], sa[7]);
    }
    __syncthreads();

    int csel[TOPK], lpos[TOPK];
    if (t < 64) {
        float sv[32];
        #pragma unroll
        for (int cq = 0; cq < 8; ++cq) {
            float4 v = *(const float4*)&simsb[t][cq * 4];
            sv[cq*4+0] = v.x; sv[cq*4+1] = v.y; sv[cq*4+2] = v.z; sv[cq*4+3] = v.w;
        }
        #pragma unroll
        for (int k = 0; k < TOPK; ++k) {
            float best = -INFINITY; int bi = 0;
            #pragma unroll
            for (int cc = 0; cc < 32; ++cc) {
                bool gt = sv[cc] > best;
                best = gt ? sv[cc] : best;
                bi   = gt ? cc : bi;
            }
            #pragma unroll
            for (int cc = 0; cc < 32; ++cc)
                if (cc == bi) sv[cc] = -INFINITY;
            csel[k] = bi;
            lpos[k] = atomicAdd(&lds_cnt[bi], 1);
        }
    }
    __syncthreads();

    if (t < 32) lds_base[t] = atomicAdd(&cur[h * 32 + t], lds_cnt[t]);
    __syncthreads();

    if (t < 64) {
        #pragma unroll
        for (int k = 0; k < TOPK; ++k) {
            int c = csel[k];
            int pos = lds_base[c] + lpos[k];
            if (pos < QCAP)
                qlist[(size_t)(h * 32 + c) * QCAP + pos] = (unsigned short)(s0 + t);
        }
    }
}

// ---------------------------------------------------------------------------
// GEMM-ified chunk-centric attention (v4). Block = (slot, hc), 256 thr.
//  - K^T[64d][64k] + V[64k][64d] staged once per block (~32 KB LDS)
//  - per 64-query tile: gather+transpose Q -> GEMM1 (4x4 micro-tile) ->
//    exp in regs -> denom via 16-lane shuffles -> P (q-major) -> GEMM2 ->
//    atomics. No K/V in registers => ~60 VGPR; dense FMA chains give ILP
//    (the R8 lesson: don't buy ILP with occupancy).
// ---------------------------------------------------------------------------
__global__ __launch_bounds__(256) void moc_attn4(const float* __restrict__ Q,
                                                 const float* __restrict__ K,
                                                 const float* __restrict__ V,
                                                 const int* __restrict__ cnt,
                                                 const unsigned short* __restrict__ qlist,
                                                 float* __restrict__ lacc,
                                                 float* __restrict__ Ob) {
    __shared__ float KT[64][64];          // [dim][key]   reads: 2-way (free)
    __shared__ float Vs[64][64];          // [key][dim]   linear staging, free reads
    __shared__ float QP[64][68];          // union: Qs[dim][q] -> P[q][key]
    __shared__ unsigned short slist[64];

    const int hc = blockIdx.y;
    const int h  = hc >> 5;
    const int c  = hc & 31;
    const int g  = blockIdx.x;            // 0..AGSPLIT-1
    const int t  = threadIdx.x;
    const int tx = t & 15;
    const int ty = t >> 4;

    const float* Kb = K + ((size_t)c * 64) * D_DIM + h * HD;
    const float* Vb = V + ((size_t)c * 64) * D_DIM + h * HD;

    // ---- stage K^T (scalar transpose writes, 4-way) ----
    {
        int j  = t >> 2;                  // key row
        int d0 = (t & 3) * 16;
        #pragma unroll
        for (int f = 0; f < 4; ++f) {
            float4 kv = *(const float4*)&Kb[(size_t)j * D_DIM + d0 + f * 4];
            KT[d0+f*4+0][j] = kv.x; KT[d0+f*4+1][j] = kv.y;
            KT[d0+f*4+2][j] = kv.z; KT[d0+f*4+3][j] = kv.w;
        }
    }
    // ---- stage V natural (lane-linear LDS writes: conflict-free) ----
    for (int i = t; i < 64 * 16; i += 256) {
        int r = i >> 4, cq = i & 15;
        *(float4*)&Vs[r][cq * 4] = *(const float4*)&Vb[(size_t)r * D_DIM + cq * 4];
    }

    const int count = min(cnt[hc], QCAP);
    const unsigned short* list = qlist + (size_t)hc * QCAP;
    const int lo = (count * g) / AGSPLIT;
    const int hi = (count * (g + 1)) / AGSPLIT;

    for (int base = lo; base < hi; base += 64) {
        __syncthreads();                              // B0: prior tile's reads done (and staging, first iter)
        if (t < 64) {
            int idx = base + t;
            slist[t] = (idx < hi) ? list[idx] : (unsigned short)0xFFFF;
        }
        __syncthreads();                              // B1: slist ready

        // ---- gather + transpose Q tile into QP[dim][q] ----
        {
            int r = t >> 2;
            unsigned short sv = slist[r];
            int s = (sv == 0xFFFF) ? 0 : (int)sv;     // pad rows load row 0 (values unused)
            const float* qp = Q + (size_t)s * D_DIM + h * HD + (t & 3) * 16;
            #pragma unroll
            for (int f = 0; f < 4; ++f) {
                float4 qv = *(const float4*)&qp[f * 4];
                int d = (t & 3) * 16 + f * 4;
                QP[d+0][r] = qv.x; QP[d+1][r] = qv.y;
                QP[d+2][r] = qv.z; QP[d+3][r] = qv.w;
            }
        }
        __syncthreads();                              // B2: Qs ready

        // ---- GEMM1: scores[4q][4k], inner over 64 dims ----
        float4 sc[4] = { make_float4(0,0,0,0), make_float4(0,0,0,0),
                         make_float4(0,0,0,0), make_float4(0,0,0,0) };
        #pragma unroll 8
        for (int d = 0; d < 64; ++d) {
            float4 a = *(const float4*)&QP[d][ty * 4];   // 4 queries (broadcast over tx)
            float4 b = *(const float4*)&KT[d][tx * 4];   // 4 keys (2-way, free)
            sc[0].x += a.x*b.x; sc[0].y += a.x*b.y; sc[0].z += a.x*b.z; sc[0].w += a.x*b.w;
            sc[1].x += a.y*b.x; sc[1].y += a.y*b.y; sc[1].z += a.y*b.z; sc[1].w += a.y*b.w;
            sc[2].x += a.z*b.x; sc[2].y += a.z*b.y; sc[2].z += a.z*b.z; sc[2].w += a.z*b.w;
            sc[3].x += a.w*b.x; sc[3].y += a.w*b.y; sc[3].z += a.w*b.z; sc[3].w += a.w*b.w;
        }
        // ---- exp + per-query denominator (reduce over the 16 tx lanes) ----
        float p[4][4];
        float ls[4];
        #pragma unroll
        for (int qi = 0; qi < 4; ++qi) {
            p[qi][0] = __expf(sc[qi].x * SCALE);
            p[qi][1] = __expf(sc[qi].y * SCALE);
            p[qi][2] = __expf(sc[qi].z * SCALE);
            p[qi][3] = __expf(sc[qi].w * SCALE);
            float v = p[qi][0] + p[qi][1] + p[qi][2] + p[qi][3];
            v += __shfl_xor(v, 1, 64);
            v += __shfl_xor(v, 2, 64);
            v += __shfl_xor(v, 4, 64);
            v += __shfl_xor(v, 8, 64);
            ls[qi] = v;                                // full row sum (all 16 tx)
        }
        if (tx == 0) {
            #pragma unroll
            for (int qi = 0; qi < 4; ++qi) {
                unsigned short sv = slist[ty * 4 + qi];
                if (sv != 0xFFFF) atomicAdd(&lacc[h * S_LEN + (int)sv], ls[qi]);
            }
        }
        __syncthreads();                              // B3: GEMM1's QP reads done

        // ---- write P (q-major) into QP[q][key] ----
        #pragma unroll
        for (int qi = 0; qi < 4; ++qi)
            *(float4*)&QP[ty * 4 + qi][tx * 4] =
                make_float4(p[qi][0], p[qi][1], p[qi][2], p[qi][3]);
        __syncthreads();                              // B4: P ready

        // ---- GEMM2: O[4q][4d], inner over 64 keys ----
        float4 oa[4] = { make_float4(0,0,0,0), make_float4(0,0,0,0),
                         make_float4(0,0,0,0), make_float4(0,0,0,0) };
        #pragma unroll 8
        for (int kk = 0; kk < 64; ++kk) {
            float4 b = *(const float4*)&Vs[kk][tx * 4];  // 4 dims (2-way, free)
            float a0 = QP[ty * 4 + 0][kk];               // broadcast over tx
            float a1 = QP[ty * 4 + 1][kk];
            float a2 = QP[ty * 4 + 2][kk];
            float a3 = QP[ty * 4 + 3][kk];
            oa[0].x += a0*b.x; oa[0].y += a0*b.y; oa[0].z += a0*b.z; oa[0].w += a0*b.w;
            oa[1].x += a1*b.x; oa[1].y += a1*b.y; oa[1].z += a1*b.z; oa[1].w += a1*b.w;
            oa[2].x += a2*b.x; oa[2].y += a2*b.y; oa[2].z += a2*b.z; oa[2].w += a2*b.w;
            oa[3].x += a3*b.x; oa[3].y += a3*b.y; oa[3].z += a3*b.z; oa[3].w += a3*b.w;
        }
        // ---- accumulate numerator ----
        #pragma unroll
        for (int qi = 0; qi < 4; ++qi) {
            unsigned short sv = slist[ty * 4 + qi];
            if (sv != 0xFFFF) {
                float* dst = Ob + (size_t)sv * D_DIM + h * HD + tx * 4;
                atomicAdd(&dst[0], oa[qi].x);
                atomicAdd(&dst[1], oa[qi].y);
                atomicAdd(&dst[2], oa[qi].z);
                atomicAdd(&dst[3], oa[qi].w);
            }
        }
    }
}

// ---------------------------------------------------------------------------
// Workspace: Qb 4MB | Kb 4MB | Vb 4MB | Ob 4MB | ck 64KB | lacc 64KB
//            | cur 1KB | qlist (ushort, 512KB)  == 17,433,600 B total
// (identical layout to passing rounds 7/8)
// ---------------------------------------------------------------------------
extern "C" void kernel_launch(void* const* d_in, const int* in_sizes, int n_in,
                              void* d_out, int out_size, void* d_ws, size_t ws_size,
                              hipStream_t stream) {
    const float* x  = (const float*)d_in[0];
    const float* Wq = (const float*)d_in[1];
    const float* Wk = (const float*)d_in[2];
    const float* Wv = (const float*)d_in[3];
    const float* Wo = (const float*)d_in[4];
    float* out = (float*)d_out;

    const size_t SD = (size_t)S_LEN * D_DIM;   // 1048576
    float* ws   = (float*)d_ws;
    float* Qb   = ws;
    float* Kb   = Qb + SD;
    float* Vb   = Kb + SD;
    float* Ob   = Vb + SD;
    float* ck   = Ob + SD;                       // [32][512]
    float* lacc = ck + (size_t)C_NUM * D_DIM;    // [H][S]
    int*   curb = (int*)(lacc + (size_t)H_NUM * S_LEN);        // [256]
    unsigned short* qlst = (unsigned short*)(curb + 256);      // [256][QCAP]

    zero_acc<<<(int)(SD / 4 / 256), 256, 0, stream>>>((float4*)Ob, (float4*)lacc, curb);

    dim3 qkvgrid(D_DIM / BN, S_LEN / BM, 3);     // 768 blocks
    gemm_qkv<<<qkvgrid, 256, 0, stream>>>(x, Wq, Wk, Wv, Qb, Kb, Vb);

    chunk_keys_kernel<<<(C_NUM * D_DIM) / 256, 256, 0, stream>>>(Kb, ck);

    dim3 rgrid(S_LEN / 64, H_NUM);               // (32, 8)
    sims_topk<<<rgrid, 256, 0, stream>>>(Qb, ck, curb, qlst);

    dim3 agrid(AGSPLIT, H_NUM * C_NUM);          // (3, 256) = 768 blocks
    moc_attn4<<<agrid, 256, 0, stream>>>(Qb, Kb, Vb, curb, qlst, lacc, Ob);

    dim3 ogrid(D_DIM / BN, S_LEN / BM);          // (8, 32)
    gemm_out<<<ogrid, 256, 0, stream>>>(Ob, Wo, out, lacc);
}

// Round 10
// 213.087 us; speedup vs baseline: 1.3221x; 1.1311x over previous
//
#include <hip/hip_runtime.h>
#include <math.h>

// Problem constants (B=1)
#define S_LEN 2048
#define D_DIM 512
#define H_NUM 8
#define HD    64
#define C_NUM 32
#define TOPK  5
#define SCALE 0.125f   // hd^-0.5
#define QCAP  1024     // fixed qlist capacity per (h,c); load is ~320
#define ATILES 16      // query tiles per (h,c): covers QCAP; empties exit fast

// ---------------------------------------------------------------------------
// GEMM: C[M,N] = A[M,K] @ B[K,N], fp32 vector-ALU, 64x64 tile, BK=32,
// software-pipelined global loads (next k-tile loads overlap the FMA loop).
// ---------------------------------------------------------------------------
#define BM 64
#define BN 64
#define BK 32

__device__ __forceinline__ void gemm_body(const float* __restrict__ A,
                                          const float* __restrict__ B,
                                          float* __restrict__ C,
                                          int M, int N, int K,
                                          int bx, int by) {
    __shared__ float As[BK][BM + 4];
    __shared__ float Bs[BK][BN];

    const int t  = threadIdx.x;
    const int tx = t & 15;
    const int ty = t >> 4;
    const int m0 = by * BM;
    const int n0 = bx * BN;

    float4 acc0 = make_float4(0.f,0.f,0.f,0.f);
    float4 acc1 = make_float4(0.f,0.f,0.f,0.f);
    float4 acc2 = make_float4(0.f,0.f,0.f,0.f);
    float4 acc3 = make_float4(0.f,0.f,0.f,0.f);

    const int ar = t >> 3;        // 0..31
    const int ac = (t & 7) * 4;   // 0..28
    const int br = t >> 4;        // 0..15
    const int bc = (t & 15) * 4;  // 0..60

    float4 a0, a1, b0, b1;
    auto LD = [&](int k0) {
        a0 = *(const float4*)&A[(size_t)(m0 + ar)      * K + k0 + ac];
        a1 = *(const float4*)&A[(size_t)(m0 + ar + 32) * K + k0 + ac];
        b0 = *(const float4*)&B[(size_t)(k0 + br)      * N + n0 + bc];
        b1 = *(const float4*)&B[(size_t)(k0 + br + 16) * N + n0 + bc];
    };

    LD(0);
    for (int k0 = 0; k0 < K; k0 += BK) {
        __syncthreads();
        As[ac+0][ar]    = a0.x; As[ac+1][ar]    = a0.y; As[ac+2][ar]    = a0.z; As[ac+3][ar]    = a0.w;
        As[ac+0][ar+32] = a1.x; As[ac+1][ar+32] = a1.y; As[ac+2][ar+32] = a1.z; As[ac+3][ar+32] = a1.w;
        *(float4*)&Bs[br][bc]      = b0;
        *(float4*)&Bs[br + 16][bc] = b1;
        __syncthreads();

        if (k0 + BK < K) LD(k0 + BK);

        #pragma unroll
        for (int kk = 0; kk < BK; ++kk) {
            float4 a = *(const float4*)&As[kk][ty * 4];
            float4 b = *(const float4*)&Bs[kk][tx * 4];
            acc0.x += a.x*b.x; acc0.y += a.x*b.y; acc0.z += a.x*b.z; acc0.w += a.x*b.w;
            acc1.x += a.y*b.x; acc1.y += a.y*b.y; acc1.z += a.y*b.z; acc1.w += a.y*b.w;
            acc2.x += a.z*b.x; acc2.y += a.z*b.y; acc2.z += a.z*b.z; acc2.w += a.z*b.w;
            acc3.x += a.w*b.x; acc3.y += a.w*b.y; acc3.z += a.w*b.z; acc3.w += a.w*b.w;
        }
    }

    *(float4*)&C[(size_t)(m0 + ty*4 + 0) * N + n0 + tx*4] = acc0;
    *(float4*)&C[(size_t)(m0 + ty*4 + 1) * N + n0 + tx*4] = acc1;
    *(float4*)&C[(size_t)(m0 + ty*4 + 2) * N + n0 + tx*4] = acc2;
    *(float4*)&C[(size_t)(m0 + ty*4 + 3) * N + n0 + tx*4] = acc3;
}

__global__ __launch_bounds__(256) void gemm_qkv(const float* __restrict__ A,
                                                const float* __restrict__ Wq,
                                                const float* __restrict__ Wk,
                                                const float* __restrict__ Wv,
                                                float* __restrict__ Qb,
                                                float* __restrict__ Kb,
                                                float* __restrict__ Vb) {
    const float* B = (blockIdx.z == 0) ? Wq : (blockIdx.z == 1) ? Wk : Wv;
    float*       C = (blockIdx.z == 0) ? Qb : (blockIdx.z == 1) ? Kb : Vb;
    gemm_body(A, B, C, S_LEN, D_DIM, D_DIM, blockIdx.x, blockIdx.y);
}

__global__ __launch_bounds__(256) void gemm_out(const float* __restrict__ Obn,
                                                const float* __restrict__ Wo,
                                                float* __restrict__ out) {
    gemm_body(Obn, Wo, out, S_LEN, D_DIM, D_DIM, blockIdx.x, blockIdx.y);
}

// ---------------------------------------------------------------------------
// Zero the routing counters (only state needing init now).
// ---------------------------------------------------------------------------
__global__ void zero_cur(int* __restrict__ cur) {
    cur[threadIdx.x] = 0;
}

// ---------------------------------------------------------------------------
// chunk_keys[c][dcol] = mean over 64 rows of K[(c*64+r)][dcol]; ck is [32][512]
// ---------------------------------------------------------------------------
__global__ __launch_bounds__(256) void chunk_keys_kernel(const float* __restrict__ K,
                                                         float* __restrict__ ck) {
    int i = blockIdx.x * 256 + threadIdx.x;    // 0..16383
    int c = i >> 9;
    int d = i & 511;
    const float* p = K + (size_t)c * 64 * D_DIM + d;
    float sum = 0.f;
    #pragma unroll
    for (int r = 0; r < 64; ++r) sum += p[(size_t)r * D_DIM];
    ck[(size_t)c * D_DIM + d] = sum * (1.0f / 64.0f);
}

// ---------------------------------------------------------------------------
// Fused sims + top-5 + scatter. qlist entries pack rank k (bits 11..13)
// with the query id (bits 0..10) -> unique-writer slot (k,h,s) downstream.
// ---------------------------------------------------------------------------
__global__ __launch_bounds__(256) void sims_topk(const float* __restrict__ Q,
                                                 const float* __restrict__ ck,
                                                 int* __restrict__ cur,
                                                 unsigned short* __restrict__ qlist) {
    __shared__ float qtile[64][68];
    __shared__ float cks[32][68];
    __shared__ float simsb[64][36];
    __shared__ int   lds_cnt[32];
    __shared__ int   lds_base[32];

    const int t  = threadIdx.x;
    const int s0 = blockIdx.x * 64;
    const int h  = blockIdx.y;

    if (t < 32) lds_cnt[t] = 0;

    {
        int r = t >> 2;
        #pragma unroll
        for (int i = 0; i < 4; ++i) {
            int cf4 = (t & 3) * 4 + i;
            *(float4*)&qtile[r][cf4 * 4] =
                *(const float4*)&Q[(size_t)(s0 + r) * D_DIM + h * HD + cf4 * 4];
        }
    }
    for (int i = t; i < C_NUM * 16; i += 256) {
        int c = i >> 4, df4 = i & 15;
        *(float4*)&cks[c][df4 * 4] =
            *(const float4*)&ck[(size_t)c * D_DIM + h * HD + df4 * 4];
    }
    __syncthreads();

    {
        const int sl = t >> 2, g = t & 3;
        float sa[8] = {0.f,0.f,0.f,0.f,0.f,0.f,0.f,0.f};
        #pragma unroll
        for (int d4 = 0; d4 < 16; ++d4) {
            float4 q4 = *(const float4*)&qtile[sl][d4 * 4];
            #pragma unroll
            for (int j = 0; j < 8; ++j) {
                float4 c4 = *(const float4*)&cks[g * 8 + j][d4 * 4];
                sa[j] += q4.x*c4.x + q4.y*c4.y + q4.z*c4.z + q4.w*c4.w;
            }
        }
        *(float4*)&simsb[sl][g*8 + 0] = make_float4(sa[0], sa[1], sa[2], sa[3]);
        *(float4*)&simsb[sl][g*8 + 4] = make_float4(sa[4], sa[5], sa[6], sa[7]);
    }
    __syncthreads();

    int csel[TOPK], lpos[TOPK];
    if (t < 64) {
        float sv[32];
        #pragma unroll
        for (int cq = 0; cq < 8; ++cq) {
            float4 v = *(const float4*)&simsb[t][cq * 4];
            sv[cq*4+0] = v.x; sv[cq*4+1] = v.y; sv[cq*4+2] = v.z; sv[cq*4+3] = v.w;
        }
        #pragma unroll
        for (int k = 0; k < TOPK; ++k) {
            float best = -INFINITY; int bi = 0;
            #pragma unroll
            for (int cc = 0; cc < 32; ++cc) {
                bool gt = sv[cc] > best;
                best = gt ? sv[cc] : best;
                bi   = gt ? cc : bi;
            }
            #pragma unroll
            for (int cc = 0; cc < 32; ++cc)
                if (cc == bi) sv[cc] = -INFINITY;
            csel[k] = bi;
            lpos[k] = atomicAdd(&lds_cnt[bi], 1);
        }
    }
    __syncthreads();

    if (t < 32) lds_base[t] = atomicAdd(&cur[h * 32 + t], lds_cnt[t]);
    __syncthreads();

    if (t < 64) {
        #pragma unroll
        for (int k = 0; k < TOPK; ++k) {
            int c = csel[k];
            int pos = lds_base[c] + lpos[k];
            if (pos < QCAP)
                qlist[(size_t)(h * 32 + c) * QCAP + pos] =
                    (unsigned short)((s0 + t) | (k << 11));
        }
    }
}

// ---------------------------------------------------------------------------
// GEMM-ified chunk-centric attention v5 — NO global atomics.
// Block = (tile g, hc). One 64-query tile per block; empty tiles exit.
// K^T + V staged in LDS; GEMM1 -> exp -> denom shuffle -> P -> GEMM2.
// Results go to unique-writer slots Opart[k][h][s][64] / lpart[k][h][s]
// via plain coalesced float4 stores (rank k unpacked from qlist entry).
// ---------------------------------------------------------------------------
__global__ __launch_bounds__(256) void moc_attn5(const float* __restrict__ Q,
                                                 const float* __restrict__ K,
                                                 const float* __restrict__ V,
                                                 const int* __restrict__ cnt,
                                                 const unsigned short* __restrict__ qlist,
                                                 float* __restrict__ lpart,
                                                 float* __restrict__ Opart) {
    __shared__ float KT[64][64];          // [dim][key]
    __shared__ float Vs[64][64];          // [key][dim]
    __shared__ float QP[64][68];          // union: Qs[dim][q] -> P[q][key]
    __shared__ unsigned short slist[64];

    const int hc = blockIdx.y;
    const int h  = hc >> 5;
    const int c  = hc & 31;
    const int g  = blockIdx.x;            // 0..ATILES-1
    const int t  = threadIdx.x;
    const int tx = t & 15;
    const int ty = t >> 4;

    const int count = min(cnt[hc], QCAP);
    const int base  = g * 64;
    if (base >= count) return;            // uniform: whole block exits
    const int lim = min(count - base, 64);

    const float* Kb = K + ((size_t)c * 64) * D_DIM + h * HD;
    const float* Vb = V + ((size_t)c * 64) * D_DIM + h * HD;
    const unsigned short* list = qlist + (size_t)hc * QCAP + base;

    // ---- stage K^T ----
    {
        int j  = t >> 2;                  // key row
        int d0 = (t & 3) * 16;
        #pragma unroll
        for (int f = 0; f < 4; ++f) {
            float4 kv = *(const float4*)&Kb[(size_t)j * D_DIM + d0 + f * 4];
            KT[d0+f*4+0][j] = kv.x; KT[d0+f*4+1][j] = kv.y;
            KT[d0+f*4+2][j] = kv.z; KT[d0+f*4+3][j] = kv.w;
        }
    }
    // ---- stage V natural ----
    for (int i = t; i < 64 * 16; i += 256) {
        int r = i >> 4, cq = i & 15;
        *(float4*)&Vs[r][cq * 4] = *(const float4*)&Vb[(size_t)r * D_DIM + cq * 4];
    }
    // ---- slist + gather/transpose Q tile (list read direct from global) ----
    if (t < 64)
        slist[t] = (t < lim) ? list[t] : (unsigned short)0xFFFF;
    {
        int r = t >> 2;
        unsigned short v = (r < lim) ? list[r] : (unsigned short)0xFFFF;
        int s = (v == 0xFFFF) ? 0 : (int)(v & 2047);
        const float* qp = Q + (size_t)s * D_DIM + h * HD + (t & 3) * 16;
        #pragma unroll
        for (int f = 0; f < 4; ++f) {
            float4 qv = *(const float4*)&qp[f * 4];
            int d = (t & 3) * 16 + f * 4;
            QP[d+0][r] = qv.x; QP[d+1][r] = qv.y;
            QP[d+2][r] = qv.z; QP[d+3][r] = qv.w;
        }
    }
    __syncthreads();                      // B1: KT, Vs, slist, Qs all ready

    // ---- GEMM1: scores[4q][4k] over 64 dims ----
    float4 sc[4] = { make_float4(0,0,0,0), make_float4(0,0,0,0),
                     make_float4(0,0,0,0), make_float4(0,0,0,0) };
    #pragma unroll 8
    for (int d = 0; d < 64; ++d) {
        float4 a = *(const float4*)&QP[d][ty * 4];   // 4 queries (broadcast)
        float4 b = *(const float4*)&KT[d][tx * 4];   // 4 keys (2-way, free)
        sc[0].x += a.x*b.x; sc[0].y += a.x*b.y; sc[0].z += a.x*b.z; sc[0].w += a.x*b.w;
        sc[1].x += a.y*b.x; sc[1].y += a.y*b.y; sc[1].z += a.y*b.z; sc[1].w += a.y*b.w;
        sc[2].x += a.z*b.x; sc[2].y += a.z*b.y; sc[2].z += a.z*b.z; sc[2].w += a.z*b.w;
        sc[3].x += a.w*b.x; sc[3].y += a.w*b.y; sc[3].z += a.w*b.z; sc[3].w += a.w*b.w;
    }
    // ---- exp + per-query denominator (reduce over 16 tx lanes) ----
    float p[4][4], ls[4];
    #pragma unroll
    for (int qi = 0; qi < 4; ++qi) {
        p[qi][0] = __expf(sc[qi].x * SCALE);
        p[qi][1] = __expf(sc[qi].y * SCALE);
        p[qi][2] = __expf(sc[qi].z * SCALE);
        p[qi][3] = __expf(sc[qi].w * SCALE);
        float v = p[qi][0] + p[qi][1] + p[qi][2] + p[qi][3];
        v += __shfl_xor(v, 1, 64);
        v += __shfl_xor(v, 2, 64);
        v += __shfl_xor(v, 4, 64);
        v += __shfl_xor(v, 8, 64);
        ls[qi] = v;
    }
    if (tx == 0) {
        #pragma unroll
        for (int qi = 0; qi < 4; ++qi) {
            unsigned short sv = slist[ty * 4 + qi];
            if (sv != 0xFFFF) {
                int k = sv >> 11, s = sv & 2047;
                lpart[((size_t)k * H_NUM + h) * S_LEN + s] = ls[qi];   // unique writer
            }
        }
    }
    __syncthreads();                      // B2: GEMM1's QP reads done

    // ---- write P (q-major) into QP[q][key] ----
    #pragma unroll
    for (int qi = 0; qi < 4; ++qi)
        *(float4*)&QP[ty * 4 + qi][tx * 4] =
            make_float4(p[qi][0], p[qi][1], p[qi][2], p[qi][3]);
    __syncthreads();                      // B3: P ready

    // ---- GEMM2: O[4q][4d] over 64 keys ----
    float4 oa[4] = { make_float4(0,0,0,0), make_float4(0,0,0,0),
                     make_float4(0,0,0,0), make_float4(0,0,0,0) };
    #pragma unroll 8
    for (int kk = 0; kk < 64; ++kk) {
        float4 b = *(const float4*)&Vs[kk][tx * 4];  // 4 dims (2-way, free)
        float a0 = QP[ty * 4 + 0][kk];               // broadcast
        float a1 = QP[ty * 4 + 1][kk];
        float a2 = QP[ty * 4 + 2][kk];
        float a3 = QP[ty * 4 + 3][kk];
        oa[0].x += a0*b.x; oa[0].y += a0*b.y; oa[0].z += a0*b.z; oa[0].w += a0*b.w;
        oa[1].x += a1*b.x; oa[1].y += a1*b.y; oa[1].z += a1*b.z; oa[1].w += a1*b.w;
        oa[2].x += a2*b.x; oa[2].y += a2*b.y; oa[2].z += a2*b.z; oa[2].w += a2*b.w;
        oa[3].x += a3*b.x; oa[3].y += a3*b.y; oa[3].z += a3*b.z; oa[3].w += a3*b.w;
    }
    // ---- plain coalesced stores to unique-writer slots ----
    #pragma unroll
    for (int qi = 0; qi < 4; ++qi) {
        unsigned short sv = slist[ty * 4 + qi];
        if (sv != 0xFFFF) {
            int k = sv >> 11, s = sv & 2047;
            float* dst = Opart + ((((size_t)k * H_NUM + h) * S_LEN + s) * HD) + tx * 4;
            *(float4*)dst = oa[qi];
        }
    }
}

// ---------------------------------------------------------------------------
// Obn[s][h*64+d] = (sum_k Opart[k][h][s][d]) / (sum_k lpart[k][h][s])
// One float4 per thread; 1024 blocks.
// ---------------------------------------------------------------------------
__global__ __launch_bounds__(256) void reduce_norm(const float4* __restrict__ Opart4,
                                                   const float* __restrict__ lpart,
                                                   float4* __restrict__ Obn4) {
    int i = blockIdx.x * 256 + threadIdx.x;   // 0..262143 float4s over [S][128]
    int s    = i >> 7;
    int col4 = i & 127;
    int h    = col4 >> 4;
    int f4   = col4 & 15;
    float4 acc = make_float4(0.f,0.f,0.f,0.f);
    float  den = 0.f;
    #pragma unroll
    for (int k = 0; k < TOPK; ++k) {
        size_t slot = ((size_t)k * H_NUM + h) * S_LEN + s;
        float4 v = Opart4[slot * 16 + f4];
        acc.x += v.x; acc.y += v.y; acc.z += v.z; acc.w += v.w;
        den += lpart[slot];
    }
    float inv = 1.0f / den;
    Obn4[i] = make_float4(acc.x*inv, acc.y*inv, acc.z*inv, acc.w*inv);
}

// ---------------------------------------------------------------------------
// Workspace layout (floats unless noted):
//   Qb 4MB (reused as Obn after attention) | Kb 4MB | Vb 4MB | ck 64KB
//   | lpart [5][8][2048] 320KB | cur 1KB | qlist ushort [256][1024] 512KB
//   | Opart [5][8][2048][64] 20MB          == ~33 MB total
// ---------------------------------------------------------------------------
extern "C" void kernel_launch(void* const* d_in, const int* in_sizes, int n_in,
                              void* d_out, int out_size, void* d_ws, size_t ws_size,
                              hipStream_t stream) {
    const float* x  = (const float*)d_in[0];
    const float* Wq = (const float*)d_in[1];
    const float* Wk = (const float*)d_in[2];
    const float* Wv = (const float*)d_in[3];
    const float* Wo = (const float*)d_in[4];
    float* out = (float*)d_out;

    const size_t SD = (size_t)S_LEN * D_DIM;   // 1048576
    float* ws    = (float*)d_ws;
    float* Qb    = ws;                                   // also Obn
    float* Kb    = Qb + SD;
    float* Vb    = Kb + SD;
    float* ck    = Vb + SD;                              // [32][512]
    float* lpart = ck + (size_t)C_NUM * D_DIM;           // [5][8][2048]
    int*   curb  = (int*)(lpart + (size_t)TOPK * H_NUM * S_LEN);   // [256]
    unsigned short* qlst = (unsigned short*)(curb + 256);          // [256][QCAP]
    float* Opart = (float*)(qlst + (size_t)256 * QCAP);            // [5][8][2048][64]

    zero_cur<<<1, 256, 0, stream>>>(curb);

    dim3 qkvgrid(D_DIM / BN, S_LEN / BM, 3);     // 768 blocks
    gemm_qkv<<<qkvgrid, 256, 0, stream>>>(x, Wq, Wk, Wv, Qb, Kb, Vb);

    chunk_keys_kernel<<<(C_NUM * D_DIM) / 256, 256, 0, stream>>>(Kb, ck);

    dim3 rgrid(S_LEN / 64, H_NUM);               // (32, 8)
    sims_topk<<<rgrid, 256, 0, stream>>>(Qb, ck, curb, qlst);

    dim3 agrid(ATILES, H_NUM * C_NUM);           // (16, 256); empties exit
    moc_attn5<<<agrid, 256, 0, stream>>>(Qb, Kb, Vb, curb, qlst, lpart, Opart);

    reduce_norm<<<(int)(SD / 4 / 256), 256, 0, stream>>>((const float4*)Opart, lpart, (float4*)Qb);

    dim3 ogrid(D_DIM / BN, S_LEN / BM);          // (8, 32)
    gemm_out<<<ogrid, 256, 0, stream>>>(Qb, Wo, out);
}

// Round 11
// 180.219 us; speedup vs baseline: 1.5633x; 1.1824x over previous
//
#include <hip/hip_runtime.h>
#include <hip/hip_bf16.h>
#include <math.h>

// Problem constants (B=1)
#define S_LEN 2048
#define D_DIM 512
#define H_NUM 8
#define HD    64
#define C_NUM 32
#define TOPK  5
#define SCALE 0.125f   // hd^-0.5
#define QCAP  1024     // fixed qlist capacity per (h,c); load is ~320
#define ATILES 16      // query tiles per (h,c); empties exit fast

typedef __attribute__((ext_vector_type(8))) short bf16x8;   // 8 bf16 (4 VGPRs)
typedef __attribute__((ext_vector_type(4))) float f32x4;

__device__ __forceinline__ unsigned short f2b(float f) {
    __hip_bfloat16 h = __float2bfloat16(f);
    unsigned short u;
    __builtin_memcpy(&u, &h, 2);
    return u;
}
__device__ __forceinline__ bf16x8 pack8(float4 a, float4 b) {
    bf16x8 r;
    r[0] = (short)f2b(a.x); r[1] = (short)f2b(a.y);
    r[2] = (short)f2b(a.z); r[3] = (short)f2b(a.w);
    r[4] = (short)f2b(b.x); r[5] = (short)f2b(b.y);
    r[6] = (short)f2b(b.z); r[7] = (short)f2b(b.w);
    return r;
}
__device__ __forceinline__ float b2f(unsigned short u) {
    __hip_bfloat16 h;
    __builtin_memcpy(&h, &u, 2);
    return __bfloat162float(h);
}

// ---------------------------------------------------------------------------
// GEMM: C[M,N] = A[M,K] @ B[K,N], fp32 vector-ALU, 64x64 tile, BK=32,
// software-pipelined global loads. (fp32 kept: routing needs fp32-faithful
// Q/K; gemm_out kept fp32 this round.)
// ---------------------------------------------------------------------------
#define BM 64
#define BN 64
#define BK 32

__device__ __forceinline__ void gemm_body(const float* __restrict__ A,
                                          const float* __restrict__ B,
                                          float* __restrict__ C,
                                          int M, int N, int K,
                                          int bx, int by) {
    __shared__ float As[BK][BM + 4];
    __shared__ float Bs[BK][BN];

    const int t  = threadIdx.x;
    const int tx = t & 15;
    const int ty = t >> 4;
    const int m0 = by * BM;
    const int n0 = bx * BN;

    float4 acc0 = make_float4(0.f,0.f,0.f,0.f);
    float4 acc1 = make_float4(0.f,0.f,0.f,0.f);
    float4 acc2 = make_float4(0.f,0.f,0.f,0.f);
    float4 acc3 = make_float4(0.f,0.f,0.f,0.f);

    const int ar = t >> 3;
    const int ac = (t & 7) * 4;
    const int br = t >> 4;
    const int bc = (t & 15) * 4;

    float4 a0, a1, b0, b1;
    auto LD = [&](int k0) {
        a0 = *(const float4*)&A[(size_t)(m0 + ar)      * K + k0 + ac];
        a1 = *(const float4*)&A[(size_t)(m0 + ar + 32) * K + k0 + ac];
        b0 = *(const float4*)&B[(size_t)(k0 + br)      * N + n0 + bc];
        b1 = *(const float4*)&B[(size_t)(k0 + br + 16) * N + n0 + bc];
    };

    LD(0);
    for (int k0 = 0; k0 < K; k0 += BK) {
        __syncthreads();
        As[ac+0][ar]    = a0.x; As[ac+1][ar]    = a0.y; As[ac+2][ar]    = a0.z; As[ac+3][ar]    = a0.w;
        As[ac+0][ar+32] = a1.x; As[ac+1][ar+32] = a1.y; As[ac+2][ar+32] = a1.z; As[ac+3][ar+32] = a1.w;
        *(float4*)&Bs[br][bc]      = b0;
        *(float4*)&Bs[br + 16][bc] = b1;
        __syncthreads();

        if (k0 + BK < K) LD(k0 + BK);

        #pragma unroll
        for (int kk = 0; kk < BK; ++kk) {
            float4 a = *(const float4*)&As[kk][ty * 4];
            float4 b = *(const float4*)&Bs[kk][tx * 4];
            acc0.x += a.x*b.x; acc0.y += a.x*b.y; acc0.z += a.x*b.z; acc0.w += a.x*b.w;
            acc1.x += a.y*b.x; acc1.y += a.y*b.y; acc1.z += a.y*b.z; acc1.w += a.y*b.w;
            acc2.x += a.z*b.x; acc2.y += a.z*b.y; acc2.z += a.z*b.z; acc2.w += a.z*b.w;
            acc3.x += a.w*b.x; acc3.y += a.w*b.y; acc3.z += a.w*b.z; acc3.w += a.w*b.w;
        }
    }

    *(float4*)&C[(size_t)(m0 + ty*4 + 0) * N + n0 + tx*4] = acc0;
    *(float4*)&C[(size_t)(m0 + ty*4 + 1) * N + n0 + tx*4] = acc1;
    *(float4*)&C[(size_t)(m0 + ty*4 + 2) * N + n0 + tx*4] = acc2;
    *(float4*)&C[(size_t)(m0 + ty*4 + 3) * N + n0 + tx*4] = acc3;
}

__global__ __launch_bounds__(256) void gemm_qkv(const float* __restrict__ A,
                                                const float* __restrict__ Wq,
                                                const float* __restrict__ Wk,
                                                const float* __restrict__ Wv,
                                                float* __restrict__ Qb,
                                                float* __restrict__ Kb,
                                                float* __restrict__ Vb) {
    const float* B = (blockIdx.z == 0) ? Wq : (blockIdx.z == 1) ? Wk : Wv;
    float*       C = (blockIdx.z == 0) ? Qb : (blockIdx.z == 1) ? Kb : Vb;
    gemm_body(A, B, C, S_LEN, D_DIM, D_DIM, blockIdx.x, blockIdx.y);
}

__global__ __launch_bounds__(256) void gemm_out(const float* __restrict__ Obn,
                                                const float* __restrict__ Wo,
                                                float* __restrict__ out) {
    gemm_body(Obn, Wo, out, S_LEN, D_DIM, D_DIM, blockIdx.x, blockIdx.y);
}

// ---------------------------------------------------------------------------
__global__ void zero_cur(int* __restrict__ cur) {
    cur[threadIdx.x] = 0;
}

// ---------------------------------------------------------------------------
// chunk_keys[c][dcol] = mean over 64 rows of K[(c*64+r)][dcol]
// ---------------------------------------------------------------------------
__global__ __launch_bounds__(256) void chunk_keys_kernel(const float* __restrict__ K,
                                                         float* __restrict__ ck) {
    int i = blockIdx.x * 256 + threadIdx.x;
    int c = i >> 9;
    int d = i & 511;
    const float* p = K + (size_t)c * 64 * D_DIM + d;
    float sum = 0.f;
    #pragma unroll
    for (int r = 0; r < 64; ++r) sum += p[(size_t)r * D_DIM];
    ck[(size_t)c * D_DIM + d] = sum * (1.0f / 64.0f);
}

// ---------------------------------------------------------------------------
// Fused sims + top-5 + scatter (fp32 — routing must stay fp32-faithful).
// qlist entries pack rank k (bits 11..13) with query id (bits 0..10).
// ---------------------------------------------------------------------------
__global__ __launch_bounds__(256) void sims_topk(const float* __restrict__ Q,
                                                 const float* __restrict__ ck,
                                                 int* __restrict__ cur,
                                                 unsigned short* __restrict__ qlist) {
    __shared__ float qtile[64][68];
    __shared__ float cks[32][68];
    __shared__ float simsb[64][36];
    __shared__ int   lds_cnt[32];
    __shared__ int   lds_base[32];

    const int t  = threadIdx.x;
    const int s0 = blockIdx.x * 64;
    const int h  = blockIdx.y;

    if (t < 32) lds_cnt[t] = 0;

    {
        int r = t >> 2;
        #pragma unroll
        for (int i = 0; i < 4; ++i) {
            int cf4 = (t & 3) * 4 + i;
            *(float4*)&qtile[r][cf4 * 4] =
                *(const float4*)&Q[(size_t)(s0 + r) * D_DIM + h * HD + cf4 * 4];
        }
    }
    for (int i = t; i < C_NUM * 16; i += 256) {
        int c = i >> 4, df4 = i & 15;
        *(float4*)&cks[c][df4 * 4] =
            *(const float4*)&ck[(size_t)c * D_DIM + h * HD + df4 * 4];
    }
    __syncthreads();

    {
        const int sl = t >> 2, g = t & 3;
        float sa[8] = {0.f,0.f,0.f,0.f,0.f,0.f,0.f,0.f};
        #pragma unroll
        for (int d4 = 0; d4 < 16; ++d4) {
            float4 q4 = *(const float4*)&qtile[sl][d4 * 4];
            #pragma unroll
            for (int j = 0; j < 8; ++j) {
                float4 c4 = *(const float4*)&cks[g * 8 + j][d4 * 4];
                sa[j] += q4.x*c4.x + q4.y*c4.y + q4.z*c4.z + q4.w*c4.w;
            }
        }
        *(float4*)&simsb[sl][g*8 + 0] = make_float4(sa[0], sa[1], sa[2], sa[3]);
        *(float4*)&simsb[sl][g*8 + 4] = make_float4(sa[4], sa[5], sa[6], sa[7]);
    }
    __syncthreads();

    int csel[TOPK], lpos[TOPK];
    if (t < 64) {
        float sv[32];
        #pragma unroll
        for (int cq = 0; cq < 8; ++cq) {
            float4 v = *(const float4*)&simsb[t][cq * 4];
            sv[cq*4+0] = v.x; sv[cq*4+1] = v.y; sv[cq*4+2] = v.z; sv[cq*4+3] = v.w;
        }
        #pragma unroll
        for (int k = 0; k < TOPK; ++k) {
            float best = -INFINITY; int bi = 0;
            #pragma unroll
            for (int cc = 0; cc < 32; ++cc) {
                bool gt = sv[cc] > best;
                best = gt ? sv[cc] : best;
                bi   = gt ? cc : bi;
            }
            #pragma unroll
            for (int cc = 0; cc < 32; ++cc)
                if (cc == bi) sv[cc] = -INFINITY;
            csel[k] = bi;
            lpos[k] = atomicAdd(&lds_cnt[bi], 1);
        }
    }
    __syncthreads();

    if (t < 32) lds_base[t] = atomicAdd(&cur[h * 32 + t], lds_cnt[t]);
    __syncthreads();

    if (t < 64) {
        #pragma unroll
        for (int k = 0; k < TOPK; ++k) {
            int c = csel[k];
            int pos = lds_base[c] + lpos[k];
            if (pos < QCAP)
                qlist[(size_t)(h * 32 + c) * QCAP + pos] =
                    (unsigned short)((s0 + t) | (k << 11));
        }
    }
}

// ---------------------------------------------------------------------------
// MFMA chunk-centric attention (v6). Block = (tile g, hc); one 64-query
// tile; 4 waves; ONE barrier.
//   staging: Ks[key][d] bf16, VT[d][key] bf16, Qs[q][d] bf16 (gathered),
//            slist  -> __syncthreads
//   GEMM1: mfma_f32_16x16x32_bf16, wave w does q-tile w x 4 key-tiles.
//     A-frag Q[m=lane&15][k=quad*8+j]; B-frag Ks[n=lane&15][k-contig].
//     C/D: col=lane&15(key), row=quad*4+reg(q).
//   exp (fp32) -> bf16 P; denom = sum of bf16-rounded p (self-consistent),
//   16-lane shuffle reduce; lpart unique-writer store.
//   Ps rows are WAVE-PRIVATE (wave w writes/reads rows w*16..+15): no barrier.
//   GEMM2: A-frag Ps[q][key-contig]; B-frag VT[d][key-contig]. Stores to
//   Opart unique-writer slots (coalesced 64B segments).
// ---------------------------------------------------------------------------
__global__ __launch_bounds__(256) void moc_attn6(const float* __restrict__ Q,
                                                 const float* __restrict__ K,
                                                 const float* __restrict__ V,
                                                 const int* __restrict__ cnt,
                                                 const unsigned short* __restrict__ qlist,
                                                 float* __restrict__ lpart,
                                                 float* __restrict__ Opart) {
    __shared__ unsigned short Qs[64][72];
    __shared__ unsigned short Ks[64][72];
    __shared__ unsigned short VT[64][72];
    __shared__ unsigned short Ps[64][72];
    __shared__ unsigned short slist[64];

    const int hc = blockIdx.y;
    const int h  = hc >> 5;
    const int c  = hc & 31;
    const int g  = blockIdx.x;
    const int t  = threadIdx.x;

    const int count = min(cnt[hc], QCAP);
    const int base  = g * 64;
    if (base >= count) return;
    const int lim = min(count - base, 64);

    const float* Kb = K + ((size_t)c * 64) * D_DIM + h * HD;
    const float* Vb = V + ((size_t)c * 64) * D_DIM + h * HD;
    const unsigned short* list = qlist + (size_t)hc * QCAP + base;

    // ---- staging: thread handles row j = t>>2, dims d0 = (t&3)*16 .. +15 ----
    {
        const int j  = t >> 2;
        const int d0 = (t & 3) * 16;

        const float* kr = Kb + (size_t)j * D_DIM + d0;
        float4 k0 = *(const float4*)&kr[0],  k1 = *(const float4*)&kr[4];
        float4 k2 = *(const float4*)&kr[8],  k3 = *(const float4*)&kr[12];
        *(bf16x8*)&Ks[j][d0]     = pack8(k0, k1);
        *(bf16x8*)&Ks[j][d0 + 8] = pack8(k2, k3);

        const float* vr = Vb + (size_t)j * D_DIM + d0;
        float4 v0 = *(const float4*)&vr[0],  v1 = *(const float4*)&vr[4];
        float4 v2 = *(const float4*)&vr[8],  v3 = *(const float4*)&vr[12];
        VT[d0+ 0][j] = f2b(v0.x); VT[d0+ 1][j] = f2b(v0.y);
        VT[d0+ 2][j] = f2b(v0.z); VT[d0+ 3][j] = f2b(v0.w);
        VT[d0+ 4][j] = f2b(v1.x); VT[d0+ 5][j] = f2b(v1.y);
        VT[d0+ 6][j] = f2b(v1.z); VT[d0+ 7][j] = f2b(v1.w);
        VT[d0+ 8][j] = f2b(v2.x); VT[d0+ 9][j] = f2b(v2.y);
        VT[d0+10][j] = f2b(v2.z); VT[d0+11][j] = f2b(v2.w);
        VT[d0+12][j] = f2b(v3.x); VT[d0+13][j] = f2b(v3.y);
        VT[d0+14][j] = f2b(v3.z); VT[d0+15][j] = f2b(v3.w);

        // gathered Q tile (row j of tile = query slist[j])
        unsigned short pv = (j < lim) ? list[j] : (unsigned short)0xFFFF;
        if ((t & 3) == 0) slist[j] = pv;
        int s = (pv == 0xFFFF) ? 0 : (int)(pv & 2047);
        const float* qr = Q + (size_t)s * D_DIM + h * HD + d0;
        float4 q0 = *(const float4*)&qr[0],  q1 = *(const float4*)&qr[4];
        float4 q2 = *(const float4*)&qr[8],  q3 = *(const float4*)&qr[12];
        *(bf16x8*)&Qs[j][d0]     = pack8(q0, q1);
        *(bf16x8*)&Qs[j][d0 + 8] = pack8(q2, q3);
    }
    __syncthreads();   // the only block-wide barrier

    const int lane = t & 63;
    const int w    = t >> 6;       // wave id = q-tile row
    const int lr   = lane & 15;
    const int quad = lane >> 4;

    // ---- GEMM1: scores[64q x 64key], wave w -> q rows w*16..+15 ----
    bf16x8 aq0 = *(const bf16x8*)&Qs[w * 16 + lr][quad * 8];
    bf16x8 aq1 = *(const bf16x8*)&Qs[w * 16 + lr][32 + quad * 8];

    f32x4 acc[4];
    #pragma unroll
    for (int kt = 0; kt < 4; ++kt) {
        bf16x8 b0 = *(const bf16x8*)&Ks[kt * 16 + lr][quad * 8];
        bf16x8 b1 = *(const bf16x8*)&Ks[kt * 16 + lr][32 + quad * 8];
        f32x4 z = {0.f, 0.f, 0.f, 0.f};
        z = __builtin_amdgcn_mfma_f32_16x16x32_bf16(aq0, b0, z, 0, 0, 0);
        z = __builtin_amdgcn_mfma_f32_16x16x32_bf16(aq1, b1, z, 0, 0, 0);
        acc[kt] = z;
    }

    // ---- exp (fp32) -> bf16 P; denominator from bf16-rounded values ----
    unsigned short pb[4][4];
    float dsum[4] = {0.f, 0.f, 0.f, 0.f};   // per reg r (q = quad*4+r)
    #pragma unroll
    for (int kt = 0; kt < 4; ++kt) {
        #pragma unroll
        for (int r = 0; r < 4; ++r) {
            unsigned short u = f2b(__expf(acc[kt][r] * SCALE));
            pb[kt][r] = u;
            dsum[r] += b2f(u);
        }
    }
    #pragma unroll
    for (int r = 0; r < 4; ++r) {
        float v = dsum[r];
        v += __shfl_xor(v, 1, 64);
        v += __shfl_xor(v, 2, 64);
        v += __shfl_xor(v, 4, 64);
        v += __shfl_xor(v, 8, 64);
        dsum[r] = v;                         // denom for q = w*16 + quad*4 + r
    }
    if (lr == 0) {
        #pragma unroll
        for (int r = 0; r < 4; ++r) {
            unsigned short sv = slist[w * 16 + quad * 4 + r];
            if (sv != 0xFFFF) {
                int kk = sv >> 11, s = sv & 2047;
                lpart[((size_t)kk * H_NUM + h) * S_LEN + s] = dsum[r];
            }
        }
    }

    // ---- P -> LDS (wave-private rows; no block barrier needed) ----
    #pragma unroll
    for (int kt = 0; kt < 4; ++kt)
        #pragma unroll
        for (int r = 0; r < 4; ++r)
            Ps[w * 16 + quad * 4 + r][kt * 16 + lr] = pb[kt][r];

    // ---- GEMM2: O[64q x 64d], wave w -> q rows w*16..+15 ----
    bf16x8 ap0 = *(const bf16x8*)&Ps[w * 16 + lr][quad * 8];
    bf16x8 ap1 = *(const bf16x8*)&Ps[w * 16 + lr][32 + quad * 8];

    #pragma unroll
    for (int dt = 0; dt < 4; ++dt) {
        bf16x8 b0 = *(const bf16x8*)&VT[dt * 16 + lr][quad * 8];
        bf16x8 b1 = *(const bf16x8*)&VT[dt * 16 + lr][32 + quad * 8];
        f32x4 z = {0.f, 0.f, 0.f, 0.f};
        z = __builtin_amdgcn_mfma_f32_16x16x32_bf16(ap0, b0, z, 0, 0, 0);
        z = __builtin_amdgcn_mfma_f32_16x16x32_bf16(ap1, b1, z, 0, 0, 0);
        // C/D: col = lane&15 = d within tile, row = quad*4+reg = q within tile
        #pragma unroll
        for (int r = 0; r < 4; ++r) {
            unsigned short sv = slist[w * 16 + quad * 4 + r];
            if (sv != 0xFFFF) {
                int kk = sv >> 11, s = sv & 2047;
                Opart[((((size_t)kk * H_NUM + h) * S_LEN + s) * HD) + dt * 16 + lr] = z[r];
            }
        }
    }
}

// ---------------------------------------------------------------------------
// Obn[s][h*64+d] = (sum_k Opart[k][h][s][d]) / (sum_k lpart[k][h][s])
// ---------------------------------------------------------------------------
__global__ __launch_bounds__(256) void reduce_norm(const float4* __restrict__ Opart4,
                                                   const float* __restrict__ lpart,
                                                   float4* __restrict__ Obn4) {
    int i = blockIdx.x * 256 + threadIdx.x;
    int s    = i >> 7;
    int col4 = i & 127;
    int h    = col4 >> 4;
    int f4   = col4 & 15;
    float4 acc = make_float4(0.f,0.f,0.f,0.f);
    float  den = 0.f;
    #pragma unroll
    for (int k = 0; k < TOPK; ++k) {
        size_t slot = ((size_t)k * H_NUM + h) * S_LEN + s;
        float4 v = Opart4[slot * 16 + f4];
        acc.x += v.x; acc.y += v.y; acc.z += v.z; acc.w += v.w;
        den += lpart[slot];
    }
    float inv = 1.0f / den;
    Obn4[i] = make_float4(acc.x*inv, acc.y*inv, acc.z*inv, acc.w*inv);
}

// ---------------------------------------------------------------------------
// Workspace: Qb 4MB (reused as Obn) | Kb 4MB | Vb 4MB | ck 64KB
//   | lpart [5][8][2048] 320KB | cur 1KB | qlist ushort 512KB
//   | Opart [5][8][2048][64] 20MB     == ~33 MB (layout proven in round 10)
// ---------------------------------------------------------------------------
extern "C" void kernel_launch(void* const* d_in, const int* in_sizes, int n_in,
                              void* d_out, int out_size, void* d_ws, size_t ws_size,
                              hipStream_t stream) {
    const float* x  = (const float*)d_in[0];
    const float* Wq = (const float*)d_in[1];
    const float* Wk = (const float*)d_in[2];
    const float* Wv = (const float*)d_in[3];
    const float* Wo = (const float*)d_in[4];
    float* out = (float*)d_out;

    const size_t SD = (size_t)S_LEN * D_DIM;
    float* ws    = (float*)d_ws;
    float* Qb    = ws;                                   // also Obn
    float* Kb    = Qb + SD;
    float* Vb    = Kb + SD;
    float* ck    = Vb + SD;
    float* lpart = ck + (size_t)C_NUM * D_DIM;
    int*   curb  = (int*)(lpart + (size_t)TOPK * H_NUM * S_LEN);
    unsigned short* qlst = (unsigned short*)(curb + 256);
    float* Opart = (float*)(qlst + (size_t)256 * QCAP);

    zero_cur<<<1, 256, 0, stream>>>(curb);

    dim3 qkvgrid(D_DIM / BN, S_LEN / BM, 3);
    gemm_qkv<<<qkvgrid, 256, 0, stream>>>(x, Wq, Wk, Wv, Qb, Kb, Vb);

    chunk_keys_kernel<<<(C_NUM * D_DIM) / 256, 256, 0, stream>>>(Kb, ck);

    dim3 rgrid(S_LEN / 64, H_NUM);
    sims_topk<<<rgrid, 256, 0, stream>>>(Qb, ck, curb, qlst);

    dim3 agrid(ATILES, H_NUM * C_NUM);
    moc_attn6<<<agrid, 256, 0, stream>>>(Qb, Kb, Vb, curb, qlst, lpart, Opart);

    reduce_norm<<<(int)(SD / 4 / 256), 256, 0, stream>>>((const float4*)Opart, lpart, (float4*)Qb);

    dim3 ogrid(D_DIM / BN, S_LEN / BM);
    gemm_out<<<ogrid, 256, 0, stream>>>(Qb, Wo, out);
}

// Round 12
// 159.449 us; speedup vs baseline: 1.7669x; 1.1303x over previous
//
#include <hip/hip_runtime.h>
#include <hip/hip_bf16.h>
#include <math.h>

// Problem constants (B=1)
#define S_LEN 2048
#define D_DIM 512
#define H_NUM 8
#define HD    64
#define C_NUM 32
#define TOPK  5
#define SCALE 0.125f   // hd^-0.5
#define QCAP  1024     // fixed qlist capacity per (h,c); load is ~320
#define ATILES 16      // query tiles per (h,c); empties exit fast

typedef __attribute__((ext_vector_type(8))) short bf16x8;   // 8 bf16 (4 VGPRs)
typedef __attribute__((ext_vector_type(4))) float f32x4;
typedef __attribute__((ext_vector_type(4))) unsigned short us4;

__device__ __forceinline__ unsigned short f2b(float f) {
    __hip_bfloat16 h = __float2bfloat16(f);
    unsigned short u;
    __builtin_memcpy(&u, &h, 2);
    return u;
}
__device__ __forceinline__ bf16x8 pack8(float4 a, float4 b) {
    bf16x8 r;
    r[0] = (short)f2b(a.x); r[1] = (short)f2b(a.y);
    r[2] = (short)f2b(a.z); r[3] = (short)f2b(a.w);
    r[4] = (short)f2b(b.x); r[5] = (short)f2b(b.y);
    r[6] = (short)f2b(b.z); r[7] = (short)f2b(b.w);
    return r;
}
__device__ __forceinline__ float b2f(unsigned short u) {
    __hip_bfloat16 h;
    __builtin_memcpy(&h, &u, 2);
    return __bfloat162float(h);
}

// ---------------------------------------------------------------------------
// fp32 GEMM (UNCHANGED BODY — Q/K must stay byte-identical: routing top-5
// near-ties flip under any reordering; flips cost ~1e-2 absmax).
// ---------------------------------------------------------------------------
#define BM 64
#define BN 64
#define BK 32

__device__ __forceinline__ void gemm_body(const float* __restrict__ A,
                                          const float* __restrict__ B,
                                          float* __restrict__ C,
                                          int M, int N, int K,
                                          int bx, int by) {
    __shared__ float As[BK][BM + 4];
    __shared__ float Bs[BK][BN];

    const int t  = threadIdx.x;
    const int tx = t & 15;
    const int ty = t >> 4;
    const int m0 = by * BM;
    const int n0 = bx * BN;

    float4 acc0 = make_float4(0.f,0.f,0.f,0.f);
    float4 acc1 = make_float4(0.f,0.f,0.f,0.f);
    float4 acc2 = make_float4(0.f,0.f,0.f,0.f);
    float4 acc3 = make_float4(0.f,0.f,0.f,0.f);

    const int ar = t >> 3;
    const int ac = (t & 7) * 4;
    const int br = t >> 4;
    const int bc = (t & 15) * 4;

    float4 a0, a1, b0, b1;
    auto LD = [&](int k0) {
        a0 = *(const float4*)&A[(size_t)(m0 + ar)      * K + k0 + ac];
        a1 = *(const float4*)&A[(size_t)(m0 + ar + 32) * K + k0 + ac];
        b0 = *(const float4*)&B[(size_t)(k0 + br)      * N + n0 + bc];
        b1 = *(const float4*)&B[(size_t)(k0 + br + 16) * N + n0 + bc];
    };

    LD(0);
    for (int k0 = 0; k0 < K; k0 += BK) {
        __syncthreads();
        As[ac+0][ar]    = a0.x; As[ac+1][ar]    = a0.y; As[ac+2][ar]    = a0.z; As[ac+3][ar]    = a0.w;
        As[ac+0][ar+32] = a1.x; As[ac+1][ar+32] = a1.y; As[ac+2][ar+32] = a1.z; As[ac+3][ar+32] = a1.w;
        *(float4*)&Bs[br][bc]      = b0;
        *(float4*)&Bs[br + 16][bc] = b1;
        __syncthreads();

        if (k0 + BK < K) LD(k0 + BK);

        #pragma unroll
        for (int kk = 0; kk < BK; ++kk) {
            float4 a = *(const float4*)&As[kk][ty * 4];
            float4 b = *(const float4*)&Bs[kk][tx * 4];
            acc0.x += a.x*b.x; acc0.y += a.x*b.y; acc0.z += a.x*b.z; acc0.w += a.x*b.w;
            acc1.x += a.y*b.x; acc1.y += a.y*b.y; acc1.z += a.y*b.z; acc1.w += a.y*b.w;
            acc2.x += a.z*b.x; acc2.y += a.z*b.y; acc2.z += a.z*b.z; acc2.w += a.z*b.w;
            acc3.x += a.w*b.x; acc3.y += a.w*b.y; acc3.z += a.w*b.z; acc3.w += a.w*b.w;
        }
    }

    *(float4*)&C[(size_t)(m0 + ty*4 + 0) * N + n0 + tx*4] = acc0;
    *(float4*)&C[(size_t)(m0 + ty*4 + 1) * N + n0 + tx*4] = acc1;
    *(float4*)&C[(size_t)(m0 + ty*4 + 2) * N + n0 + tx*4] = acc2;
    *(float4*)&C[(size_t)(m0 + ty*4 + 3) * N + n0 + tx*4] = acc3;
}

// Q and K projections only (z in {0,1}); math byte-identical to round 11.
__global__ __launch_bounds__(256) void gemm_qkv(const float* __restrict__ A,
                                                const float* __restrict__ Wq,
                                                const float* __restrict__ Wk,
                                                float* __restrict__ Qb,
                                                float* __restrict__ Kb) {
    const float* B = (blockIdx.z == 0) ? Wq : Wk;
    float*       C = (blockIdx.z == 0) ? Qb : Kb;
    gemm_body(A, B, C, S_LEN, D_DIM, D_DIM, blockIdx.x, blockIdx.y);
}

// ---------------------------------------------------------------------------
// bf16 MFMA GEMM: C[M,N] = A[M,K] @ B[K,N]. 64x64 tile, BK=64, 4 waves,
// wave w owns rows w*16..+15. A staged [m][k] bf16; B staged transposed
// [n][k] bf16 (scalar transpose writes, ~4-way = cheap, off hot path).
// Fragments per R11-verified layouts: A[m=lane&15][k=quad*8+j],
// B[n=lane&15][k contig]; C/D row=quad*4+reg (m), col=lane&15 (n).
// ---------------------------------------------------------------------------
template <bool ABF16, bool CBF16>
__device__ __forceinline__ void gemm_bf16_body(const void* __restrict__ Aptr,
                                               const float* __restrict__ B,
                                               void* __restrict__ Cptr,
                                               int M, int N, int K,
                                               int bx, int by) {
    __shared__ unsigned short As[64][72];
    __shared__ unsigned short Bs[64][72];

    const int t  = threadIdx.x;
    const int m0 = by * 64;
    const int n0 = bx * 64;
    const int rl = t >> 2;          // 0..63
    const int c4 = (t & 3) * 16;    // col offset (elements)

    const int lane = t & 63, w = t >> 6, lr = lane & 15, quad = lane >> 4;

    f32x4 acc[4] = {{0.f,0.f,0.f,0.f},{0.f,0.f,0.f,0.f},
                    {0.f,0.f,0.f,0.f},{0.f,0.f,0.f,0.f}};

    float4 fa[4]; bf16x8 ba[2]; float4 fb[4];
    auto LDA = [&](int k0) {
        if (ABF16) {
            const unsigned short* A = (const unsigned short*)Aptr;
            ba[0] = *(const bf16x8*)&A[(size_t)(m0 + rl) * K + k0 + c4];
            ba[1] = *(const bf16x8*)&A[(size_t)(m0 + rl) * K + k0 + c4 + 8];
        } else {
            const float* A = (const float*)Aptr;
            const float* p = &A[(size_t)(m0 + rl) * K + k0 + c4];
            fa[0] = *(const float4*)&p[0];  fa[1] = *(const float4*)&p[4];
            fa[2] = *(const float4*)&p[8];  fa[3] = *(const float4*)&p[12];
        }
    };
    auto LDB = [&](int k0) {
        const float* p = &B[(size_t)(k0 + rl) * N + n0 + c4];
        fb[0] = *(const float4*)&p[0];  fb[1] = *(const float4*)&p[4];
        fb[2] = *(const float4*)&p[8];  fb[3] = *(const float4*)&p[12];
    };

    LDA(0); LDB(0);
    for (int k0 = 0; k0 < K; k0 += 64) {
        __syncthreads();
        if (ABF16) {
            *(bf16x8*)&As[rl][c4]     = ba[0];
            *(bf16x8*)&As[rl][c4 + 8] = ba[1];
        } else {
            *(bf16x8*)&As[rl][c4]     = pack8(fa[0], fa[1]);
            *(bf16x8*)&As[rl][c4 + 8] = pack8(fa[2], fa[3]);
        }
        #pragma unroll
        for (int f = 0; f < 4; ++f) {   // B transpose: Bs[n][k]
            float4 v = fb[f];
            Bs[c4 + f*4 + 0][rl] = f2b(v.x);
            Bs[c4 + f*4 + 1][rl] = f2b(v.y);
            Bs[c4 + f*4 + 2][rl] = f2b(v.z);
            Bs[c4 + f*4 + 3][rl] = f2b(v.w);
        }
        __syncthreads();

        if (k0 + 64 < K) { LDA(k0 + 64); LDB(k0 + 64); }

        bf16x8 a0 = *(const bf16x8*)&As[w * 16 + lr][quad * 8];
        bf16x8 a1 = *(const bf16x8*)&As[w * 16 + lr][32 + quad * 8];
        #pragma unroll
        for (int nt = 0; nt < 4; ++nt) {
            bf16x8 b0 = *(const bf16x8*)&Bs[nt * 16 + lr][quad * 8];
            bf16x8 b1 = *(const bf16x8*)&Bs[nt * 16 + lr][32 + quad * 8];
            acc[nt] = __builtin_amdgcn_mfma_f32_16x16x32_bf16(a0, b0, acc[nt], 0, 0, 0);
            acc[nt] = __builtin_amdgcn_mfma_f32_16x16x32_bf16(a1, b1, acc[nt], 0, 0, 0);
        }
    }

    #pragma unroll
    for (int nt = 0; nt < 4; ++nt)
        #pragma unroll
        for (int r = 0; r < 4; ++r) {
            int m = m0 + w * 16 + quad * 4 + r;
            int n = n0 + nt * 16 + lr;
            if (CBF16) ((unsigned short*)Cptr)[(size_t)m * N + n] = f2b(acc[nt][r]);
            else       ((float*)Cptr)[(size_t)m * N + n] = acc[nt][r];
        }
}

// V projection -> bf16 output (V is bf16-quantized inside attention anyway).
// Block (0,0) also zeroes the routing counters (saves a dispatch).
__global__ __launch_bounds__(256) void gemm_v(const float* __restrict__ x,
                                              const float* __restrict__ Wv,
                                              unsigned short* __restrict__ Vbf,
                                              int* __restrict__ cur) {
    if (blockIdx.x == 0 && blockIdx.y == 0) cur[threadIdx.x] = 0;
    gemm_bf16_body<false, true>(x, Wv, Vbf, S_LEN, D_DIM, D_DIM,
                                blockIdx.x, blockIdx.y);
}

// Output projection: bf16 A (normalized attention out), fp32 C.
__global__ __launch_bounds__(256) void gemm_out(const unsigned short* __restrict__ Obn,
                                                const float* __restrict__ Wo,
                                                float* __restrict__ out) {
    gemm_bf16_body<true, false>(Obn, Wo, out, S_LEN, D_DIM, D_DIM,
                                blockIdx.x, blockIdx.y);
}

// ---------------------------------------------------------------------------
// chunk_keys[c][dcol] = mean over 64 rows of K (fp32 — feeds routing).
// ---------------------------------------------------------------------------
__global__ __launch_bounds__(256) void chunk_keys_kernel(const float* __restrict__ K,
                                                         float* __restrict__ ck) {
    int i = blockIdx.x * 256 + threadIdx.x;
    int c = i >> 9;
    int d = i & 511;
    const float* p = K + (size_t)c * 64 * D_DIM + d;
    float sum = 0.f;
    #pragma unroll
    for (int r = 0; r < 64; ++r) sum += p[(size_t)r * D_DIM];
    ck[(size_t)c * D_DIM + d] = sum * (1.0f / 64.0f);
}

// ---------------------------------------------------------------------------
// Fused sims + top-5 + scatter (fp32, unchanged — routing-faithful).
// ---------------------------------------------------------------------------
__global__ __launch_bounds__(256) void sims_topk(const float* __restrict__ Q,
                                                 const float* __restrict__ ck,
                                                 int* __restrict__ cur,
                                                 unsigned short* __restrict__ qlist) {
    __shared__ float qtile[64][68];
    __shared__ float cks[32][68];
    __shared__ float simsb[64][36];
    __shared__ int   lds_cnt[32];
    __shared__ int   lds_base[32];

    const int t  = threadIdx.x;
    const int s0 = blockIdx.x * 64;
    const int h  = blockIdx.y;

    if (t < 32) lds_cnt[t] = 0;

    {
        int r = t >> 2;
        #pragma unroll
        for (int i = 0; i < 4; ++i) {
            int cf4 = (t & 3) * 4 + i;
            *(float4*)&qtile[r][cf4 * 4] =
                *(const float4*)&Q[(size_t)(s0 + r) * D_DIM + h * HD + cf4 * 4];
        }
    }
    for (int i = t; i < C_NUM * 16; i += 256) {
        int c = i >> 4, df4 = i & 15;
        *(float4*)&cks[c][df4 * 4] =
            *(const float4*)&ck[(size_t)c * D_DIM + h * HD + df4 * 4];
    }
    __syncthreads();

    {
        const int sl = t >> 2, g = t & 3;
        float sa[8] = {0.f,0.f,0.f,0.f,0.f,0.f,0.f,0.f};
        #pragma unroll
        for (int d4 = 0; d4 < 16; ++d4) {
            float4 q4 = *(const float4*)&qtile[sl][d4 * 4];
            #pragma unroll
            for (int j = 0; j < 8; ++j) {
                float4 c4 = *(const float4*)&cks[g * 8 + j][d4 * 4];
                sa[j] += q4.x*c4.x + q4.y*c4.y + q4.z*c4.z + q4.w*c4.w;
            }
        }
        *(float4*)&simsb[sl][g*8 + 0] = make_float4(sa[0], sa[1], sa[2], sa[3]);
        *(float4*)&simsb[sl][g*8 + 4] = make_float4(sa[4], sa[5], sa[6], sa[7]);
    }
    __syncthreads();

    int csel[TOPK], lpos[TOPK];
    if (t < 64) {
        float sv[32];
        #pragma unroll
        for (int cq = 0; cq < 8; ++cq) {
            float4 v = *(const float4*)&simsb[t][cq * 4];
            sv[cq*4+0] = v.x; sv[cq*4+1] = v.y; sv[cq*4+2] = v.z; sv[cq*4+3] = v.w;
        }
        #pragma unroll
        for (int k = 0; k < TOPK; ++k) {
            float best = -INFINITY; int bi = 0;
            #pragma unroll
            for (int cc = 0; cc < 32; ++cc) {
                bool gt = sv[cc] > best;
                best = gt ? sv[cc] : best;
                bi   = gt ? cc : bi;
            }
            #pragma unroll
            for (int cc = 0; cc < 32; ++cc)
                if (cc == bi) sv[cc] = -INFINITY;
            csel[k] = bi;
            lpos[k] = atomicAdd(&lds_cnt[bi], 1);
        }
    }
    __syncthreads();

    if (t < 32) lds_base[t] = atomicAdd(&cur[h * 32 + t], lds_cnt[t]);
    __syncthreads();

    if (t < 64) {
        #pragma unroll
        for (int k = 0; k < TOPK; ++k) {
            int c = csel[k];
            int pos = lds_base[c] + lpos[k];
            if (pos < QCAP)
                qlist[(size_t)(h * 32 + c) * QCAP + pos] =
                    (unsigned short)((s0 + t) | (k << 11));
        }
    }
}

// ---------------------------------------------------------------------------
// MFMA chunk-centric attention (v6, V source now bf16). One barrier.
// ---------------------------------------------------------------------------
__global__ __launch_bounds__(256) void moc_attn6(const float* __restrict__ Q,
                                                 const float* __restrict__ K,
                                                 const unsigned short* __restrict__ Vbf,
                                                 const int* __restrict__ cnt,
                                                 const unsigned short* __restrict__ qlist,
                                                 float* __restrict__ lpart,
                                                 float* __restrict__ Opart) {
    __shared__ unsigned short Qs[64][72];
    __shared__ unsigned short Ks[64][72];
    __shared__ unsigned short VT[64][72];
    __shared__ unsigned short Ps[64][72];
    __shared__ unsigned short slist[64];

    const int hc = blockIdx.y;
    const int h  = hc >> 5;
    const int c  = hc & 31;
    const int g  = blockIdx.x;
    const int t  = threadIdx.x;

    const int count = min(cnt[hc], QCAP);
    const int base  = g * 64;
    if (base >= count) return;
    const int lim = min(count - base, 64);

    const float* Kb = K + ((size_t)c * 64) * D_DIM + h * HD;
    const unsigned short* Vb = Vbf + ((size_t)c * 64) * D_DIM + h * HD;
    const unsigned short* list = qlist + (size_t)hc * QCAP + base;

    {
        const int j  = t >> 2;
        const int d0 = (t & 3) * 16;

        const float* kr = Kb + (size_t)j * D_DIM + d0;
        float4 k0 = *(const float4*)&kr[0],  k1 = *(const float4*)&kr[4];
        float4 k2 = *(const float4*)&kr[8],  k3 = *(const float4*)&kr[12];
        *(bf16x8*)&Ks[j][d0]     = pack8(k0, k1);
        *(bf16x8*)&Ks[j][d0 + 8] = pack8(k2, k3);

        const unsigned short* vr = Vb + (size_t)j * D_DIM + d0;
        bf16x8 v0 = *(const bf16x8*)&vr[0];
        bf16x8 v1 = *(const bf16x8*)&vr[8];
        #pragma unroll
        for (int i = 0; i < 8; ++i) {
            VT[d0 + i][j]     = (unsigned short)v0[i];
            VT[d0 + 8 + i][j] = (unsigned short)v1[i];
        }

        unsigned short pv = (j < lim) ? list[j] : (unsigned short)0xFFFF;
        if ((t & 3) == 0) slist[j] = pv;
        int s = (pv == 0xFFFF) ? 0 : (int)(pv & 2047);
        const float* qr = Q + (size_t)s * D_DIM + h * HD + d0;
        float4 q0 = *(const float4*)&qr[0],  q1 = *(const float4*)&qr[4];
        float4 q2 = *(const float4*)&qr[8],  q3 = *(const float4*)&qr[12];
        *(bf16x8*)&Qs[j][d0]     = pack8(q0, q1);
        *(bf16x8*)&Qs[j][d0 + 8] = pack8(q2, q3);
    }
    __syncthreads();

    const int lane = t & 63;
    const int w    = t >> 6;
    const int lr   = lane & 15;
    const int quad = lane >> 4;

    bf16x8 aq0 = *(const bf16x8*)&Qs[w * 16 + lr][quad * 8];
    bf16x8 aq1 = *(const bf16x8*)&Qs[w * 16 + lr][32 + quad * 8];

    f32x4 acc[4];
    #pragma unroll
    for (int kt = 0; kt < 4; ++kt) {
        bf16x8 b0 = *(const bf16x8*)&Ks[kt * 16 + lr][quad * 8];
        bf16x8 b1 = *(const bf16x8*)&Ks[kt * 16 + lr][32 + quad * 8];
        f32x4 z = {0.f, 0.f, 0.f, 0.f};
        z = __builtin_amdgcn_mfma_f32_16x16x32_bf16(aq0, b0, z, 0, 0, 0);
        z = __builtin_amdgcn_mfma_f32_16x16x32_bf16(aq1, b1, z, 0, 0, 0);
        acc[kt] = z;
    }

    unsigned short pb[4][4];
    float dsum[4] = {0.f, 0.f, 0.f, 0.f};
    #pragma unroll
    for (int kt = 0; kt < 4; ++kt) {
        #pragma unroll
        for (int r = 0; r < 4; ++r) {
            unsigned short u = f2b(__expf(acc[kt][r] * SCALE));
            pb[kt][r] = u;
            dsum[r] += b2f(u);
        }
    }
    #pragma unroll
    for (int r = 0; r < 4; ++r) {
        float v = dsum[r];
        v += __shfl_xor(v, 1, 64);
        v += __shfl_xor(v, 2, 64);
        v += __shfl_xor(v, 4, 64);
        v += __shfl_xor(v, 8, 64);
        dsum[r] = v;
    }
    if (lr == 0) {
        #pragma unroll
        for (int r = 0; r < 4; ++r) {
            unsigned short sv = slist[w * 16 + quad * 4 + r];
            if (sv != 0xFFFF) {
                int kk = sv >> 11, s = sv & 2047;
                lpart[((size_t)kk * H_NUM + h) * S_LEN + s] = dsum[r];
            }
        }
    }

    #pragma unroll
    for (int kt = 0; kt < 4; ++kt)
        #pragma unroll
        for (int r = 0; r < 4; ++r)
            Ps[w * 16 + quad * 4 + r][kt * 16 + lr] = pb[kt][r];

    bf16x8 ap0 = *(const bf16x8*)&Ps[w * 16 + lr][quad * 8];
    bf16x8 ap1 = *(const bf16x8*)&Ps[w * 16 + lr][32 + quad * 8];

    #pragma unroll
    for (int dt = 0; dt < 4; ++dt) {
        bf16x8 b0 = *(const bf16x8*)&VT[dt * 16 + lr][quad * 8];
        bf16x8 b1 = *(const bf16x8*)&VT[dt * 16 + lr][32 + quad * 8];
        f32x4 z = {0.f, 0.f, 0.f, 0.f};
        z = __builtin_amdgcn_mfma_f32_16x16x32_bf16(ap0, b0, z, 0, 0, 0);
        z = __builtin_amdgcn_mfma_f32_16x16x32_bf16(ap1, b1, z, 0, 0, 0);
        #pragma unroll
        for (int r = 0; r < 4; ++r) {
            unsigned short sv = slist[w * 16 + quad * 4 + r];
            if (sv != 0xFFFF) {
                int kk = sv >> 11, s = sv & 2047;
                Opart[((((size_t)kk * H_NUM + h) * S_LEN + s) * HD) + dt * 16 + lr] = z[r];
            }
        }
    }
}

// ---------------------------------------------------------------------------
// Obn_bf[s][h*64+d] = bf16( (sum_k Opart[k][h][s][d]) / (sum_k lpart) )
// ---------------------------------------------------------------------------
__global__ __launch_bounds__(256) void reduce_norm(const float4* __restrict__ Opart4,
                                                   const float* __restrict__ lpart,
                                                   unsigned short* __restrict__ Obn) {
    int i = blockIdx.x * 256 + threadIdx.x;   // one float4-slot per thread
    int s    = i >> 7;
    int col4 = i & 127;
    int h    = col4 >> 4;
    int f4   = col4 & 15;
    float4 acc = make_float4(0.f,0.f,0.f,0.f);
    float  den = 0.f;
    #pragma unroll
    for (int k = 0; k < TOPK; ++k) {
        size_t slot = ((size_t)k * H_NUM + h) * S_LEN + s;
        float4 v = Opart4[slot * 16 + f4];
        acc.x += v.x; acc.y += v.y; acc.z += v.z; acc.w += v.w;
        den += lpart[slot];
    }
    float inv = 1.0f / den;
    us4 o;
    o[0] = f2b(acc.x * inv); o[1] = f2b(acc.y * inv);
    o[2] = f2b(acc.z * inv); o[3] = f2b(acc.w * inv);
    *(us4*)&Obn[(size_t)i * 4] = o;
}

// ---------------------------------------------------------------------------
// Workspace: Qb 4MB (reused as Obn bf16 2MB) | Kb 4MB | Vbf ushort 2MB
//   | ck 64KB | lpart 320KB | cur 1KB | qlist 512KB | Opart 20MB  ≈ 31 MB
// ---------------------------------------------------------------------------
extern "C" void kernel_launch(void* const* d_in, const int* in_sizes, int n_in,
                              void* d_out, int out_size, void* d_ws, size_t ws_size,
                              hipStream_t stream) {
    const float* x  = (const float*)d_in[0];
    const float* Wq = (const float*)d_in[1];
    const float* Wk = (const float*)d_in[2];
    const float* Wv = (const float*)d_in[3];
    const float* Wo = (const float*)d_in[4];
    float* out = (float*)d_out;

    const size_t SD = (size_t)S_LEN * D_DIM;
    float* ws    = (float*)d_ws;
    float* Qb    = ws;                                    // later: Obn (bf16)
    float* Kb    = Qb + SD;
    unsigned short* Vbf = (unsigned short*)(Kb + SD);     // [2048][512] bf16
    float* ck    = (float*)(Vbf + SD);
    float* lpart = ck + (size_t)C_NUM * D_DIM;
    int*   curb  = (int*)(lpart + (size_t)TOPK * H_NUM * S_LEN);
    unsigned short* qlst = (unsigned short*)(curb + 256);
    float* Opart = (float*)(qlst + (size_t)256 * QCAP);
    unsigned short* Obn = (unsigned short*)Qb;

    dim3 qkgrid(D_DIM / BN, S_LEN / BM, 2);      // Q,K fp32 (byte-identical)
    gemm_qkv<<<qkgrid, 256, 0, stream>>>(x, Wq, Wk, Qb, Kb);

    dim3 vgrid(D_DIM / 64, S_LEN / 64);          // V bf16 MFMA (+ cur zeroing)
    gemm_v<<<vgrid, 256, 0, stream>>>(x, Wv, Vbf, curb);

    chunk_keys_kernel<<<(C_NUM * D_DIM) / 256, 256, 0, stream>>>(Kb, ck);

    dim3 rgrid(S_LEN / 64, H_NUM);
    sims_topk<<<rgrid, 256, 0, stream>>>(Qb, ck, curb, qlst);

    dim3 agrid(ATILES, H_NUM * C_NUM);
    moc_attn6<<<agrid, 256, 0, stream>>>(Qb, Kb, Vbf, curb, qlst, lpart, Opart);

    reduce_norm<<<(int)(SD / 4 / 256), 256, 0, stream>>>((const float4*)Opart, lpart, Obn);

    dim3 ogrid(D_DIM / 64, S_LEN / 64);
    gemm_out<<<ogrid, 256, 0, stream>>>(Obn, Wo, out);
}